// Round 1
// 2629.616 us; speedup vs baseline: 1.7982x; 1.7982x over previous
//
#include <hip/hip_runtime.h>

#define TT 12
#define NN 512
#define CD 128
#define SLICE (CD*NN)   // 65536
#define NSL 768         // B*T

typedef __attribute__((ext_vector_type(8))) short short8;   // 8 bf16 (4 VGPRs)
typedef __attribute__((ext_vector_type(4))) float f32x4;    // MFMA C/D
typedef unsigned short u16;

__device__ __forceinline__ u16 f2bf(float f){
    union { float f; unsigned u; } v; v.f = f;
    return (u16)((v.u + 0x7FFFu + ((v.u >> 16) & 1u)) >> 16);   // RNE
}

// ---------------- start conv: X[sl][d][n] = Wst[d][:]·x0[b][:][n][t] + bst[d]; also bf16 copy ----------------
__global__ __launch_bounds__(256) void k_start(const float* __restrict__ x0,
        const float* __restrict__ Wst, const float* __restrict__ bst,
        float* __restrict__ X, u16* __restrict__ Xbf, const int s0){
    int idx = blockIdx.x*256 + threadIdx.x;          // sl*65536 + d*512 + n
    int n = idx & (NN-1);
    int d = (idx>>9) & (CD-1);
    int sl = idx >> 16;
    int s = s0 + sl;
    int b = s/TT, t = s - b*TT;
    int base = (b*2*NN + n)*TT + t;                  // x0[b][0][n][t]
    float v0 = x0[base];
    float v1 = x0[base + NN*TT];                     // ci=1
    float val = Wst[2*d]*v0 + Wst[2*d+1]*v1 + bst[d];
    X[idx] = val;
    Xbf[idx] = f2bf(val);
}

// ---------------- one-time: AT[w][v] = bf16(adj[v][w]) ----------------
__global__ __launch_bounds__(256) void k_adjT(const float* __restrict__ adj,
        u16* __restrict__ AT){
    int idx = blockIdx.x*256 + threadIdx.x;          // 512*512 total
    int v = idx >> 9, w = idx & (NN-1);              // coalesced reads
    AT[(size_t)w*NN + v] = f2bf(adj[(size_t)v*NN + w]);
}

// ---------------- node conv via MFMA: DST[sl][c][w] = sum_v Xbf[sl][c][v] * adj[v][w] ----------------
// A-operand = X tile (M=c,K=v), B-operand from AT[w][v] so frag k-reads are contiguous.
// Fragment layouts (gfx950 16x16x32 bf16): A: row=lane&15, k=(lane>>4)*8+j ;
// B: col=lane&15, k=(lane>>4)*8+j ; D: col=lane&15, row=(lane>>4)*4+r (m89-verified).
__global__ __launch_bounds__(256) void k_nconv_mx(const u16* __restrict__ Xbf,
        const u16* __restrict__ AT, float* __restrict__ DST, u16* __restrict__ DSTbf){
    __shared__ __align__(16) short As[128*72];   // [c 128][k 64 (+8 pad)] bf16
    __shared__ __align__(16) short Bs[128*72];   // [w 128][k 64 (+8 pad)] bf16
    const int t    = threadIdx.x;
    const int sl   = blockIdx.x >> 2;
    const int nb   = (blockIdx.x & 3) * 128;     // w-tile base
    const int lane = t & 63;
    const int wid  = t >> 6;
    const int wr   = (wid >> 1) * 64;            // wave row (c) offset
    const int wc   = (wid & 1)  * 64;            // wave col (w) offset
    const u16* Xs  = Xbf + (size_t)sl * SLICE;
    const u16* Bg  = AT  + (size_t)nb * NN;
    const int r0   = t >> 3;                     // 0..31
    const int co   = (t & 7) * 8;                // 0..56
    f32x4 acc[4][4] = {};                        // [c-frag][w-frag]
    for (int kb = 0; kb < NN; kb += 64) {
        #pragma unroll
        for (int p = 0; p < 4; p++) {
            int row = p*32 + r0;
            *(short8*)(As + row*72 + co) = *(const short8*)(Xs + (size_t)row*NN + kb + co);
            *(short8*)(Bs + row*72 + co) = *(const short8*)(Bg + (size_t)row*NN + kb + co);
        }
        __syncthreads();
        #pragma unroll
        for (int ks = 0; ks < 64; ks += 32) {
            const int kg = ks + ((lane >> 4) << 3);
            const int lr = lane & 15;
            short8 af[4], bfr[4];
            #pragma unroll
            for (int i = 0; i < 4; i++) af[i]  = *(const short8*)(As + (wr + i*16 + lr)*72 + kg);
            #pragma unroll
            for (int j = 0; j < 4; j++) bfr[j] = *(const short8*)(Bs + (wc + j*16 + lr)*72 + kg);
            #pragma unroll
            for (int i = 0; i < 4; i++)
                #pragma unroll
                for (int j = 0; j < 4; j++)
                    acc[i][j] = __builtin_amdgcn_mfma_f32_16x16x32_bf16(af[i], bfr[j], acc[i][j], 0, 0, 0);
        }
        __syncthreads();
    }
    const int lr = lane & 15, lh = lane >> 4;
    float* Dp = DST + (size_t)sl * SLICE;
    u16*   Bp = DSTbf ? (DSTbf + (size_t)sl * SLICE) : (u16*)0;
    #pragma unroll
    for (int i = 0; i < 4; i++){
        #pragma unroll
        for (int j = 0; j < 4; j++){
            const int c = wr + i*16 + lh*4;
            const int w = nb + wc + j*16 + lr;
            f32x4 v = acc[i][j];
            #pragma unroll
            for (int r = 0; r < 4; r++){
                Dp[(size_t)(c + r)*NN + w] = v[r];
                if (Bp) Bp[(size_t)(c + r)*NN + w] = f2bf(v[r]);
            }
        }
    }
}

// ---------------- skip conv, accumulates into out[s][n][o]; step==2 applies output BN ----------------
__global__ __launch_bounds__(256) void k_skip(const float* __restrict__ X,
        const float* __restrict__ W, const float* __restrict__ bias,
        float* __restrict__ out,
        const float* __restrict__ og, const float* __restrict__ obt,
        const float* __restrict__ om, const float* __restrict__ ov,
        const int step, const int s0){
    __shared__ float Lt[16*68];   // [k=c][n 64 (+4 pad)]
    __shared__ float Rt[16*68];   // [k=c][o 64 (+4 pad)]
    const int t   = threadIdx.x;
    const int sl  = blockIdx.x >> 4;
    const int r   = blockIdx.x & 15;
    const int nb  = (r >> 1) * 64;
    const int obk = (r & 1) * 64;
    const int tx = t & 15, ty = t >> 4;   // tx: o-group, ty: n-group
    const float* Xs = X + (size_t)sl*SLICE;
    float acc[4][4] = {};                 // [n][o]
    for (int cb = 0; cb < CD; cb += 16) {
        {   int k = t >> 4, n4 = (t & 15)*4;
            *(float4*)(Lt + k*68 + n4) = *(const float4*)(Xs + (cb+k)*NN + nb + n4); }
        {   int o = t >> 2, kg = (t & 3)*4;
            float4 w4 = *(const float4*)(W + (obk + o)*CD + cb + kg);
            Rt[(kg+0)*68 + o] = w4.x; Rt[(kg+1)*68 + o] = w4.y;
            Rt[(kg+2)*68 + o] = w4.z; Rt[(kg+3)*68 + o] = w4.w; }
        __syncthreads();
        #pragma unroll
        for (int k=0;k<16;k++){
            float4 a4 = *(const float4*)(Lt + k*68 + ty*4);
            float4 b4 = *(const float4*)(Rt + k*68 + tx*4);
            float av[4] = {a4.x,a4.y,a4.z,a4.w};
            float bv[4] = {b4.x,b4.y,b4.z,b4.w};
            #pragma unroll
            for (int i=0;i<4;i++)
                #pragma unroll
                for (int j=0;j<4;j++) acc[i][j] += av[i]*bv[j];
        }
        __syncthreads();
    }
    float bz[4], ao[4], co[4];
    #pragma unroll
    for (int j=0;j<4;j++){
        int o = obk + tx*4 + j;
        bz[j] = bias[o];
        if (step == 2) {
            float inv = og[o] * rsqrtf(ov[o] + 1e-5f);
            ao[j] = inv; co[j] = obt[o] - om[o]*inv;
        }
    }
    #pragma unroll
    for (int i=0;i<4;i++){
        int n = nb + ty*4 + i;
        float* po = out + (size_t)(s0+sl)*SLICE + n*CD + obk + tx*4;
        float v[4];
        #pragma unroll
        for (int j=0;j<4;j++) v[j] = acc[i][j] + bz[j];
        if (step > 0) {
            float4 pv = *(const float4*)po;
            v[0]+=pv.x; v[1]+=pv.y; v[2]+=pv.z; v[3]+=pv.w;
        }
        if (step == 2) {
            #pragma unroll
            for (int j=0;j<4;j++) v[j] = ao[j]*v[j] + co[j];
        }
        float4 w4; w4.x=v[0]; w4.y=v[1]; w4.z=v[2]; w4.w=v[3];
        *(float4*)po = w4;
    }
}

// ---------------- gc conv (K=384 over [X,X1,X2]) + gc BN + residual + step BN; X updated in place + bf16 copy ----------------
__global__ __launch_bounds__(256) void k_gc(float* X, u16* __restrict__ Xbf,
        const float* __restrict__ X1, const float* __restrict__ X2,
        const float* __restrict__ W, const float* __restrict__ bias,
        const float* __restrict__ gg, const float* __restrict__ gb,
        const float* __restrict__ gm, const float* __restrict__ gv,
        const float* __restrict__ bg, const float* __restrict__ bb,
        const float* __restrict__ bm, const float* __restrict__ bv){
    __shared__ float Lt[16*132];  // [k][o 128 (+4)]
    __shared__ float Rt[16*36];   // [k][n 32 (+4)]
    const int t  = threadIdx.x;
    const int sl = blockIdx.x >> 4;
    const int nb = (blockIdx.x & 15) * 32;
    const int tx = t & 7, ty = t >> 3;   // tx: n-group(8), ty: o-group(32)
    float acc[4][4] = {};                // [o][n]
    const float* srcs[3] = { X + (size_t)sl*SLICE, X1 + (size_t)sl*SLICE, X2 + (size_t)sl*SLICE };
    for (int ph = 0; ph < 3; ph++){
        const float* S  = srcs[ph];
        const float* Wp = W + ph*CD;     // W[o][ph*128 + c] = Wp[o*384 + c]
        for (int cb = 0; cb < CD; cb += 16){
            {   int o = t >> 1, kg = (t & 1)*8;
                const float* p = Wp + o*384 + cb + kg;
                float4 wa = *(const float4*)(p);
                float4 wb4 = *(const float4*)(p + 4);
                Lt[(kg+0)*132 + o] = wa.x;  Lt[(kg+1)*132 + o] = wa.y;
                Lt[(kg+2)*132 + o] = wa.z;  Lt[(kg+3)*132 + o] = wa.w;
                Lt[(kg+4)*132 + o] = wb4.x; Lt[(kg+5)*132 + o] = wb4.y;
                Lt[(kg+6)*132 + o] = wb4.z; Lt[(kg+7)*132 + o] = wb4.w; }
            if (t < 128){
                int k = t >> 3, n4 = (t & 7)*4;
                *(float4*)(Rt + k*36 + n4) = *(const float4*)(S + (cb+k)*NN + nb + n4); }
            __syncthreads();
            #pragma unroll
            for (int k=0;k<16;k++){
                float4 a4 = *(const float4*)(Lt + k*132 + ty*4);
                float4 b4 = *(const float4*)(Rt + k*36 + tx*4);
                float av[4] = {a4.x,a4.y,a4.z,a4.w};
                float bv[4] = {b4.x,b4.y,b4.z,b4.w};
                #pragma unroll
                for (int i=0;i<4;i++)
                    #pragma unroll
                    for (int j=0;j<4;j++) acc[i][j] += av[i]*bv[j];
            }
            __syncthreads();
        }
    }
    #pragma unroll
    for (int i=0;i<4;i++){
        int o = ty*4 + i;
        float h0  = bias[o];
        float ig  = gg[o] * rsqrtf(gv[o] + 1e-5f);
        float cg_ = gb[o] - gm[o]*ig;
        float ib  = bg[o] * rsqrtf(bv[o] + 1e-5f);
        float cb_ = bb[o] - bm[o]*ib;
        float* px = X + (size_t)sl*SLICE + o*NN + nb + tx*4;
        float4 rv = *(const float4*)px;
        float res[4] = {rv.x, rv.y, rv.z, rv.w};
        float v[4];
        #pragma unroll
        for (int j=0;j<4;j++)
            v[j] = ib*( ig*(acc[i][j] + h0) + cg_ + res[j] ) + cb_;
        float4 w4; w4.x=v[0]; w4.y=v[1]; w4.z=v[2]; w4.w=v[3];
        *(float4*)px = w4;
        u16* pb = Xbf + (size_t)sl*SLICE + o*NN + nb + tx*4;
        unsigned q0 = (unsigned)f2bf(v[0]) | ((unsigned)f2bf(v[1]) << 16);
        unsigned q1 = (unsigned)f2bf(v[2]) | ((unsigned)f2bf(v[3]) << 16);
        *(unsigned long long*)pb = (unsigned long long)q0 | ((unsigned long long)q1 << 32);
    }
}

extern "C" void kernel_launch(void* const* d_in, const int* in_sizes, int n_in,
                              void* d_out, int out_size, void* d_ws, size_t ws_size,
                              hipStream_t stream) {
    const float* x0   = (const float*)d_in[0];
    const float* adj  = (const float*)d_in[1];
    const float* Wst  = (const float*)d_in[2];
    const float* bst  = (const float*)d_in[3];
    const float* Wsk  = (const float*)d_in[4];
    const float* bsk  = (const float*)d_in[5];
    const float* Wgc  = (const float*)d_in[6];
    const float* bgc  = (const float*)d_in[7];
    const float* gg   = (const float*)d_in[8];
    const float* gb   = (const float*)d_in[9];
    const float* gm   = (const float*)d_in[10];
    const float* gv   = (const float*)d_in[11];
    const float* bg   = (const float*)d_in[12];
    const float* bb   = (const float*)d_in[13];
    const float* bm   = (const float*)d_in[14];
    const float* bv   = (const float*)d_in[15];
    const float* og   = (const float*)d_in[16];
    const float* obt  = (const float*)d_in[17];
    const float* om   = (const float*)d_in[18];
    const float* ov   = (const float*)d_in[19];
    float* out = (float*)d_out;            // [b][t][n][d] == [s][n][o]

    // Workspace per slice: X,X1,X2 fp32 (3*256KB) + Xbf,X1bf bf16 (2*128KB) = 1 MB.
    // Plus 512 KB for the bf16 transposed adjacency. Chunk to fit ws_size.
    static const int divs[] = {768,384,256,192,128,96,64,48,32,24,16,12,8,6,4,3,2,1};
    const size_t perSlice = (size_t)SLICE * 16;
    int SC = 1;
    for (int di = 0; di < 18; di++) {
        if ((size_t)divs[di] * perSlice + 512*1024 <= ws_size) { SC = divs[di]; break; }
    }
    float* X   = (float*)d_ws;
    float* X1  = X  + (size_t)SC*SLICE;
    float* X2  = X1 + (size_t)SC*SLICE;
    u16*  Xbf  = (u16*)(X2 + (size_t)SC*SLICE);
    u16*  X1bf = Xbf  + (size_t)SC*SLICE;
    u16*  AT   = X1bf + (size_t)SC*SLICE;

    k_adjT<<<(NN*NN)/256, 256, 0, stream>>>(adj, AT);

    for (int s0 = 0; s0 < NSL; s0 += SC) {
        k_start<<<SC*(SLICE/256), 256, 0, stream>>>(x0, Wst, bst, X, Xbf, s0);
        for (int i = 0; i < 3; i++) {
            k_skip<<<SC*16, 256, 0, stream>>>(X, Wsk + i*CD*CD, bsk + i*CD, out,
                                              og, obt, om, ov, i, s0);
            if (i == 2) break;
            k_nconv_mx<<<SC*4, 256, 0, stream>>>(Xbf,  AT, X1, X1bf);
            k_nconv_mx<<<SC*4, 256, 0, stream>>>(X1bf, AT, X2, (u16*)0);
            k_gc<<<SC*16, 256, 0, stream>>>(X, Xbf, X1, X2,
                Wgc + i*CD*384, bgc + i*CD,
                gg + i*CD, gb + i*CD, gm + i*CD, gv + i*CD,
                bg + i*CD, bb + i*CD, bm + i*CD, bv + i*CD);
        }
    }
}

// Round 2
// 1362.741 us; speedup vs baseline: 3.4700x; 1.9297x over previous
//
#include <hip/hip_runtime.h>

#define TT 12
#define NN 512
#define CD 128
#define SLICE (CD*NN)   // 65536
#define NSL 768         // B*T

typedef __attribute__((ext_vector_type(8))) short short8;   // 8 bf16 (4 VGPRs)
typedef __attribute__((ext_vector_type(4))) float f32x4;    // MFMA C/D
typedef unsigned short u16;

__device__ __forceinline__ u16 f2bf(float f){
    union { float f; unsigned u; } v; v.f = f;
    return (u16)((v.u + 0x7FFFu + ((v.u >> 16) & 1u)) >> 16);   // RNE
}

// ---------------- transpose+cast 512x512: DT[w][v] = bf16(src[v][w]) ----------------
// lanes walk v (gather reads, L2-resident 1MB); writes contiguous.
__global__ __launch_bounds__(256) void k_adjT(const float* __restrict__ src,
        u16* __restrict__ DT){
    int idx = blockIdx.x*256 + threadIdx.x;          // 512*512
    int w = idx >> 9, v = idx & (NN-1);
    DT[(size_t)w*NN + v] = f2bf(src[(size_t)v*NN + w]);
}

// ---------------- A2[u][w] = sum_v adj[u][v]*adj[v][w] (fp32, once) ----------------
__global__ __launch_bounds__(256) void k_a2(const float* __restrict__ adj,
        float* __restrict__ A2){
    int u = blockIdx.x >> 1;
    int w = (blockIdx.x & 1)*256 + threadIdx.x;
    float acc = 0.f;
    for (int v = 0; v < NN; v++) acc += adj[(size_t)u*NN+v] * adj[(size_t)v*NN+w];
    A2[(size_t)u*NN+w] = acc;
}

// ---------------- generic fp32 -> bf16 cast ----------------
__global__ __launch_bounds__(256) void k_cast(const float* __restrict__ src,
        u16* __restrict__ dst){
    int i = blockIdx.x*256 + threadIdx.x;
    dst[i] = f2bf(src[i]);
}

// ---------------- start conv: X[d][n] fp32 + Sbf[d][n] bf16 + S0T[n][d] bf16 ----------------
__global__ __launch_bounds__(256) void k_start(const float* __restrict__ x0,
        const float* __restrict__ Wst, const float* __restrict__ bst,
        float* __restrict__ X, u16* __restrict__ Sbf, u16* __restrict__ S0T,
        const int s0){
    __shared__ float Lv[2*64];
    __shared__ __align__(16) short Tt[64*136];       // [n 64][d 128 (+8)]
    const int t  = threadIdx.x;
    const int sl = blockIdx.x >> 3;
    const int n0 = (blockIdx.x & 7) * 64;
    const int s = s0 + sl;
    const int b = s / TT, tt = s - b*TT;
    if (t < 128) {
        int ci = t >> 6, nl2 = t & 63;
        Lv[ci*64 + nl2] = x0[(size_t)((b*2 + ci)*NN + n0 + nl2)*TT + tt];
    }
    __syncthreads();
    const int nl = t & 63;
    const int dg = (t >> 6) * 32;
    const float v0 = Lv[nl], v1 = Lv[64 + nl];
    const size_t base = (size_t)sl * SLICE;
    #pragma unroll 4
    for (int dd = 0; dd < 32; dd++) {
        int d = dg + dd;
        float val = Wst[2*d]*v0 + Wst[2*d+1]*v1 + bst[d];
        size_t off = base + (size_t)d*NN + n0 + nl;
        X[off] = val;
        u16 bv = f2bf(val);
        Sbf[off] = bv;
        Tt[nl*136 + d] = (short)bv;
    }
    __syncthreads();
    #pragma unroll
    for (int q = 0; q < 4; q++) {
        int id = t + q*256;
        int row = id >> 4, c0 = (id & 15) * 8;
        *(short8*)(S0T + base + (size_t)(n0 + row)*CD + c0) =
            *(const short8*)(Tt + row*136 + c0);
    }
}

// ---------------- hop GEMM: DT[w][c] = sum_v M[w][v] * S[c][v]  (M = AT or A2T) ----------------
__global__ __launch_bounds__(256) void k_hop(const u16* __restrict__ M,
        const u16* __restrict__ S, u16* __restrict__ DT){
    __shared__ __align__(16) short As[128*72];   // [w 128][k 64 (+8)]
    __shared__ __align__(16) short Bs[128*72];   // [c 128][k 64 (+8)]
    const int t    = threadIdx.x;
    const int sl   = blockIdx.x >> 2;
    const int wb   = (blockIdx.x & 3) * 128;
    const int lane = t & 63, wid = t >> 6;
    const int wr   = (wid >> 1) * 64, wc = (wid & 1) * 64;
    const int r0   = t >> 3, co = (t & 7) * 8;
    const u16* Ss  = S + (size_t)sl * SLICE;
    f32x4 acc[4][4] = {};
    for (int kb = 0; kb < NN; kb += 64) {
        #pragma unroll
        for (int p = 0; p < 4; p++) {
            int row = p*32 + r0;
            *(short8*)(As + row*72 + co) = *(const short8*)(M  + (size_t)(wb+row)*NN + kb + co);
            *(short8*)(Bs + row*72 + co) = *(const short8*)(Ss + (size_t)row*NN + kb + co);
        }
        __syncthreads();
        #pragma unroll
        for (int ks = 0; ks < 64; ks += 32) {
            const int kg = ks + ((lane >> 4) << 3);
            const int lr = lane & 15;
            short8 af[4], bfr[4];
            #pragma unroll
            for (int i = 0; i < 4; i++) af[i]  = *(const short8*)(As + (wr + i*16 + lr)*72 + kg);
            #pragma unroll
            for (int j = 0; j < 4; j++) bfr[j] = *(const short8*)(Bs + (wc + j*16 + lr)*72 + kg);
            #pragma unroll
            for (int i = 0; i < 4; i++)
                #pragma unroll
                for (int j = 0; j < 4; j++)
                    acc[i][j] = __builtin_amdgcn_mfma_f32_16x16x32_bf16(af[i], bfr[j], acc[i][j], 0, 0, 0);
        }
        __syncthreads();
    }
    const int lr = lane & 15, lh = lane >> 4;
    u16* Dp = DT + (size_t)sl * SLICE;
    #pragma unroll
    for (int i = 0; i < 4; i++)
        #pragma unroll
        for (int j = 0; j < 4; j++) {
            f32x4 v = acc[i][j];
            #pragma unroll
            for (int r = 0; r < 4; r++)
                Dp[(size_t)(wb + wr + i*16 + lh*4 + r)*CD + wc + j*16 + lr] = f2bf(v[r]);
        }
}

// ---------------- gc conv MFMA (K=384 over [ST,X1T,X2T]) + BN + residual + BN ----------------
// writes: X fp32 [o][n], Sbf bf16 [o][n], SnT bf16 [n][o] (via LDS bounce)
__global__ __launch_bounds__(256) void k_gc_mx(
        const u16* __restrict__ ST, const u16* __restrict__ X1T, const u16* __restrict__ X2T,
        const u16* __restrict__ Wg, const float* __restrict__ bias,
        float* __restrict__ X, u16* __restrict__ Sbf, u16* __restrict__ SnT,
        const float* __restrict__ gg, const float* __restrict__ gb,
        const float* __restrict__ gm, const float* __restrict__ gv,
        const float* __restrict__ bg, const float* __restrict__ bb,
        const float* __restrict__ bm, const float* __restrict__ bv){
    __shared__ __align__(16) short AB[2*128*72];   // As|Bs, re-used as Tt[128][136] in epilogue
    __shared__ float Cst[5*128];
    short* As = AB;
    short* Bs = AB + 128*72;
    short* Tt = AB;
    const int t    = threadIdx.x;
    const int sl   = blockIdx.x >> 2;
    const int nb   = (blockIdx.x & 3) * 128;
    const int lane = t & 63, wid = t >> 6;
    const int wr   = (wid >> 1) * 64, wc = (wid & 1) * 64;
    const int r0   = t >> 3, co = (t & 7) * 8;
    if (t < 128) {
        float ig = gg[t] * rsqrtf(gv[t] + 1e-5f);
        float ib = bg[t] * rsqrtf(bv[t] + 1e-5f);
        Cst[t]       = ig;
        Cst[128 + t] = gb[t] - gm[t]*ig;
        Cst[256 + t] = ib;
        Cst[384 + t] = bb[t] - bm[t]*ib;
        Cst[512 + t] = bias[t];
    }
    const u16* srcs[3] = { ST  + (size_t)sl*SLICE,
                           X1T + (size_t)sl*SLICE,
                           X2T + (size_t)sl*SLICE };
    f32x4 acc[4][4] = {};
    #pragma unroll
    for (int kb = 0; kb < 384; kb += 64) {
        const u16* Sp = srcs[kb >> 7];
        const int  kc = kb & 127;
        #pragma unroll
        for (int p = 0; p < 4; p++) {
            int row = p*32 + r0;
            *(short8*)(As + row*72 + co) = *(const short8*)(Wg + (size_t)row*384 + kb + co);
            *(short8*)(Bs + row*72 + co) = *(const short8*)(Sp + (size_t)(nb+row)*CD + kc + co);
        }
        __syncthreads();
        #pragma unroll
        for (int ks = 0; ks < 64; ks += 32) {
            const int kg = ks + ((lane >> 4) << 3);
            const int lr = lane & 15;
            short8 af[4], bfr[4];
            #pragma unroll
            for (int i = 0; i < 4; i++) af[i]  = *(const short8*)(As + (wr + i*16 + lr)*72 + kg);
            #pragma unroll
            for (int j = 0; j < 4; j++) bfr[j] = *(const short8*)(Bs + (wc + j*16 + lr)*72 + kg);
            #pragma unroll
            for (int i = 0; i < 4; i++)
                #pragma unroll
                for (int j = 0; j < 4; j++)
                    acc[i][j] = __builtin_amdgcn_mfma_f32_16x16x32_bf16(af[i], bfr[j], acc[i][j], 0, 0, 0);
        }
        __syncthreads();
    }
    const int lr = lane & 15, lh = lane >> 4;
    const size_t base = (size_t)sl * SLICE;
    #pragma unroll
    for (int i = 0; i < 4; i++)
        #pragma unroll
        for (int j = 0; j < 4; j++) {
            int nl = wc + j*16 + lr;
            f32x4 a = acc[i][j];
            #pragma unroll
            for (int r = 0; r < 4; r++) {
                int o = wr + i*16 + lh*4 + r;
                float ig = Cst[o], cg = Cst[128+o], ib = Cst[256+o];
                float cb_ = Cst[384+o], h0 = Cst[512+o];
                size_t off = base + (size_t)o*NN + nb + nl;
                float res = X[off];
                float v = ib*( ig*(a[r] + h0) + cg + res ) + cb_;
                X[off] = v;
                u16 bv2 = f2bf(v);
                Sbf[off] = bv2;
                Tt[nl*136 + o] = (short)bv2;
            }
        }
    __syncthreads();
    u16* Dp = SnT + base;
    #pragma unroll
    for (int q = 0; q < 8; q++) {
        int id = t + q*256;
        int row = id >> 4, c0 = (id & 15) * 8;
        *(short8*)(Dp + (size_t)(nb + row)*CD + c0) = *(const short8*)(Tt + row*136 + c0);
    }
}

// ---------------- fused skip: out[n][o] = BN_ob( sum_i Wsk_i·S_i + sum_i b_i ) ----------------
__global__ __launch_bounds__(256) void k_skip_fused(
        const u16* __restrict__ S0T, const u16* __restrict__ S1T, const u16* __restrict__ S2T,
        const u16* __restrict__ Wsb, const float* __restrict__ bsk,
        const float* __restrict__ og, const float* __restrict__ obt,
        const float* __restrict__ om, const float* __restrict__ ov,
        float* __restrict__ out, const int s0){
    __shared__ __align__(16) short As[128*72];   // [n 128][k 64 (+8)]
    __shared__ __align__(16) short Bs[128*72];   // [o 128][k 64 (+8)]
    __shared__ float Cst[3*128];
    const int t    = threadIdx.x;
    const int sl   = blockIdx.x >> 2;
    const int nbt  = (blockIdx.x & 3) * 128;
    const int lane = t & 63, wid = t >> 6;
    const int wr   = (wid >> 1) * 64, wc = (wid & 1) * 64;
    const int r0   = t >> 3, co = (t & 7) * 8;
    if (t < 128) {
        float inv = og[t] * rsqrtf(ov[t] + 1e-5f);
        Cst[t]       = inv;
        Cst[128 + t] = obt[t] - om[t]*inv;
        Cst[256 + t] = bsk[t] + bsk[CD + t] + bsk[2*CD + t];
    }
    const u16* srcs[3] = { S0T + (size_t)sl*SLICE,
                           S1T + (size_t)sl*SLICE,
                           S2T + (size_t)sl*SLICE };
    f32x4 acc[4][4] = {};
    #pragma unroll
    for (int kb = 0; kb < 384; kb += 64) {
        const u16* Sp = srcs[kb >> 7];
        const int  ph = kb >> 7;
        const int  kc = kb & 127;
        #pragma unroll
        for (int p = 0; p < 4; p++) {
            int row = p*32 + r0;
            *(short8*)(As + row*72 + co) = *(const short8*)(Sp + (size_t)(nbt+row)*CD + kc + co);
            *(short8*)(Bs + row*72 + co) = *(const short8*)(Wsb + (size_t)ph*CD*CD + (size_t)row*CD + kc + co);
        }
        __syncthreads();
        #pragma unroll
        for (int ks = 0; ks < 64; ks += 32) {
            const int kg = ks + ((lane >> 4) << 3);
            const int lr = lane & 15;
            short8 af[4], bfr[4];
            #pragma unroll
            for (int i = 0; i < 4; i++) af[i]  = *(const short8*)(As + (wr + i*16 + lr)*72 + kg);
            #pragma unroll
            for (int j = 0; j < 4; j++) bfr[j] = *(const short8*)(Bs + (wc + j*16 + lr)*72 + kg);
            #pragma unroll
            for (int i = 0; i < 4; i++)
                #pragma unroll
                for (int j = 0; j < 4; j++)
                    acc[i][j] = __builtin_amdgcn_mfma_f32_16x16x32_bf16(af[i], bfr[j], acc[i][j], 0, 0, 0);
        }
        __syncthreads();
    }
    const int lr = lane & 15, lh = lane >> 4;
    float* Op = out + (size_t)(s0 + sl) * SLICE;
    #pragma unroll
    for (int i = 0; i < 4; i++)
        #pragma unroll
        for (int j = 0; j < 4; j++) {
            int o = wc + j*16 + lr;
            float ao = Cst[o], c0_ = Cst[128+o], sb = Cst[256+o];
            f32x4 v = acc[i][j];
            #pragma unroll
            for (int r = 0; r < 4; r++) {
                int n = nbt + wr + i*16 + lh*4 + r;
                Op[(size_t)n*CD + o] = ao*(v[r] + sb) + c0_;
            }
        }
}

extern "C" void kernel_launch(void* const* d_in, const int* in_sizes, int n_in,
                              void* d_out, int out_size, void* d_ws, size_t ws_size,
                              hipStream_t stream) {
    const float* x0   = (const float*)d_in[0];
    const float* adj  = (const float*)d_in[1];
    const float* Wst  = (const float*)d_in[2];
    const float* bst  = (const float*)d_in[3];
    const float* Wsk  = (const float*)d_in[4];
    const float* bsk  = (const float*)d_in[5];
    const float* Wgc  = (const float*)d_in[6];
    const float* bgc  = (const float*)d_in[7];
    const float* gg   = (const float*)d_in[8];
    const float* gb   = (const float*)d_in[9];
    const float* gm   = (const float*)d_in[10];
    const float* gv   = (const float*)d_in[11];
    const float* bg   = (const float*)d_in[12];
    const float* bb   = (const float*)d_in[13];
    const float* bm   = (const float*)d_in[14];
    const float* bv   = (const float*)d_in[15];
    const float* og   = (const float*)d_in[16];
    const float* obt  = (const float*)d_in[17];
    const float* om   = (const float*)d_in[18];
    const float* ov   = (const float*)d_in[19];
    float* out = (float*)d_out;            // [s][n][o]

    // ---- workspace layout: globals first, then SC per-slice buffers ----
    float* A2f   = (float*)d_ws;                         // 1 MB
    u16*   AT    = (u16*)(A2f + NN*NN);                  // 512 KB
    u16*   A2T   = AT  + NN*NN;                          // 512 KB
    u16*   Wskbf = A2T + NN*NN;                          // 96 KB
    u16*   Wgcbf = Wskbf + 3*CD*CD;                      // 192 KB
    char*  pend  = (char*)(Wgcbf + 2*CD*384);
    size_t goff  = ((size_t)(pend - (char*)d_ws) + 255) & ~(size_t)255;

    // per-slice: X fp32 (256K) + Sbf,S0T,S1T,S2T,X1T,X2T bf16 (6*128K) = 1 MB
    static const int divs[] = {768,384,256,192,128,96,64,48,32,24,16,12,8,6,4,3,2,1};
    const size_t perSlice = (size_t)SLICE*4 + 6*(size_t)SLICE*2;
    int SC = 1;
    for (int di = 0; di < 18; di++) {
        if (goff + (size_t)divs[di]*perSlice <= ws_size) { SC = divs[di]; break; }
    }
    float* X   = (float*)((char*)d_ws + goff);
    u16*   Sbf = (u16*)(X + (size_t)SC*SLICE);
    u16*   S0T = Sbf + (size_t)SC*SLICE;
    u16*   S1T = S0T + (size_t)SC*SLICE;
    u16*   S2T = S1T + (size_t)SC*SLICE;
    u16*   X1T = S2T + (size_t)SC*SLICE;
    u16*   X2T = X1T + (size_t)SC*SLICE;

    // ---- one-time precompute ----
    k_adjT<<<(NN*NN)/256, 256, 0, stream>>>(adj, AT);
    k_a2  <<<NN*2,        256, 0, stream>>>(adj, A2f);
    k_adjT<<<(NN*NN)/256, 256, 0, stream>>>(A2f, A2T);
    k_cast<<<(3*CD*CD)/256,  256, 0, stream>>>(Wsk, Wskbf);
    k_cast<<<(2*CD*384)/256, 256, 0, stream>>>(Wgc, Wgcbf);

    for (int s0 = 0; s0 < NSL; s0 += SC) {
        k_start<<<SC*8, 256, 0, stream>>>(x0, Wst, bst, X, Sbf, S0T, s0);
        for (int i = 0; i < 2; i++) {
            k_hop<<<SC*4, 256, 0, stream>>>(AT,  Sbf, X1T);
            k_hop<<<SC*4, 256, 0, stream>>>(A2T, Sbf, X2T);
            k_gc_mx<<<SC*4, 256, 0, stream>>>(
                (i ? S1T : S0T), X1T, X2T,
                Wgcbf + (size_t)i*CD*384, bgc + i*CD,
                X, Sbf, (i ? S2T : S1T),
                gg + i*CD, gb + i*CD, gm + i*CD, gv + i*CD,
                bg + i*CD, bb + i*CD, bm + i*CD, bv + i*CD);
        }
        k_skip_fused<<<SC*4, 256, 0, stream>>>(S0T, S1T, S2T, Wskbf, bsk,
                                               og, obt, om, ov, out, s0);
    }
}

// Round 3
// 1160.520 us; speedup vs baseline: 4.0746x; 1.1743x over previous
//
#include <hip/hip_runtime.h>

#define TT 12
#define NN 512
#define CD 128
#define SLICE (CD*NN)   // 65536
#define NSL 768         // B*T

typedef __attribute__((ext_vector_type(8))) short short8;   // 8 bf16 (4 VGPRs)
typedef __attribute__((ext_vector_type(4))) float f32x4;    // MFMA C/D
typedef unsigned short u16;

__device__ __forceinline__ u16 f2bf(float f){
    union { float f; unsigned u; } v; v.f = f;
    return (u16)((v.u + 0x7FFFu + ((v.u >> 16) & 1u)) >> 16);   // RNE
}
__device__ __forceinline__ float bf2f(u16 h){
    union { unsigned u; float f; } v; v.u = ((unsigned)h) << 16;
    return v.f;
}

// ---------------- transpose+cast 512x512: DT[w][v] = bf16(src[v][w]) ----------------
__global__ __launch_bounds__(256) void k_adjT(const float* __restrict__ src,
        u16* __restrict__ DT){
    int idx = blockIdx.x*256 + threadIdx.x;          // 512*512
    int w = idx >> 9, v = idx & (NN-1);
    DT[(size_t)w*NN + v] = f2bf(src[(size_t)v*NN + w]);
}

// ---------------- A2[u][w] = sum_v adj[u][v]*adj[v][w] (fp32, once) ----------------
__global__ __launch_bounds__(256) void k_a2(const float* __restrict__ adj,
        float* __restrict__ A2){
    int u = blockIdx.x >> 1;
    int w = (blockIdx.x & 1)*256 + threadIdx.x;
    float acc = 0.f;
    for (int v = 0; v < NN; v++) acc += adj[(size_t)u*NN+v] * adj[(size_t)v*NN+w];
    A2[(size_t)u*NN+w] = acc;
}

// ---------------- generic fp32 -> bf16 cast ----------------
__global__ __launch_bounds__(256) void k_cast(const float* __restrict__ src,
        u16* __restrict__ dst){
    int i = blockIdx.x*256 + threadIdx.x;
    dst[i] = f2bf(src[i]);
}

// ---------------- start conv: Sbf[d][n] bf16 + S0T[n][d] bf16 ----------------
__global__ __launch_bounds__(256) void k_start(const float* __restrict__ x0,
        const float* __restrict__ Wst, const float* __restrict__ bst,
        u16* __restrict__ Sbf, u16* __restrict__ S0T, const int s0){
    __shared__ float Lv[2*64];
    __shared__ __align__(16) short Tt[64*136];       // [n 64][d 128 (+8)]
    const int t  = threadIdx.x;
    const int sl = blockIdx.x >> 3;
    const int n0 = (blockIdx.x & 7) * 64;
    const int s = s0 + sl;
    const int b = s / TT, tt = s - b*TT;
    if (t < 128) {
        int ci = t >> 6, nl2 = t & 63;
        Lv[ci*64 + nl2] = x0[(size_t)((b*2 + ci)*NN + n0 + nl2)*TT + tt];
    }
    __syncthreads();
    const int nl = t & 63;
    const int dg = (t >> 6) * 32;
    const float v0 = Lv[nl], v1 = Lv[64 + nl];
    const size_t base = (size_t)sl * SLICE;
    #pragma unroll 4
    for (int dd = 0; dd < 32; dd++) {
        int d = dg + dd;
        float val = Wst[2*d]*v0 + Wst[2*d+1]*v1 + bst[d];
        u16 bv = f2bf(val);
        Sbf[base + (size_t)d*NN + n0 + nl] = bv;
        Tt[nl*136 + d] = (short)bv;
    }
    __syncthreads();
    #pragma unroll
    for (int q = 0; q < 4; q++) {
        int id = t + q*256;
        int row = id >> 4, c0 = (id & 15) * 8;
        *(short8*)(S0T + base + (size_t)(n0 + row)*CD + c0) =
            *(const short8*)(Tt + row*136 + c0);
    }
}

// ---------------- fused double hop: DT[w][c] = sum_v M[w][v]*S[c][v], M in {AT, A2T} ----------------
__global__ __launch_bounds__(256) void k_hop2(const u16* __restrict__ AT,
        const u16* __restrict__ A2T, const u16* __restrict__ Sbf,
        u16* __restrict__ X1T, u16* __restrict__ X2T){
    __shared__ __align__(16) short As[128*72];   // [w 128][k 64 (+8)]
    __shared__ __align__(16) short Bs[128*72];   // [c 128][k 64 (+8)]
    const int t    = threadIdx.x;
    const int sl   = blockIdx.x >> 3;
    const int r    = blockIdx.x & 7;
    const u16* M   = (r & 4) ? A2T : AT;
    u16* DT        = (r & 4) ? X2T : X1T;
    const int wb   = (r & 3) * 128;
    const int lane = t & 63, wid = t >> 6;
    const int wr   = (wid >> 1) * 64, wc = (wid & 1) * 64;
    const int r0   = t >> 3, co = (t & 7) * 8;
    const u16* Ss  = Sbf + (size_t)sl * SLICE;
    f32x4 acc[4][4] = {};
    for (int kb = 0; kb < NN; kb += 64) {
        #pragma unroll
        for (int p = 0; p < 4; p++) {
            int row = p*32 + r0;
            *(short8*)(As + row*72 + co) = *(const short8*)(M  + (size_t)(wb+row)*NN + kb + co);
            *(short8*)(Bs + row*72 + co) = *(const short8*)(Ss + (size_t)row*NN + kb + co);
        }
        __syncthreads();
        #pragma unroll
        for (int ks = 0; ks < 64; ks += 32) {
            const int kg = ks + ((lane >> 4) << 3);
            const int lr = lane & 15;
            short8 af[4], bfr[4];
            #pragma unroll
            for (int i = 0; i < 4; i++) af[i]  = *(const short8*)(As + (wr + i*16 + lr)*72 + kg);
            #pragma unroll
            for (int j = 0; j < 4; j++) bfr[j] = *(const short8*)(Bs + (wc + j*16 + lr)*72 + kg);
            #pragma unroll
            for (int i = 0; i < 4; i++)
                #pragma unroll
                for (int j = 0; j < 4; j++)
                    acc[i][j] = __builtin_amdgcn_mfma_f32_16x16x32_bf16(af[i], bfr[j], acc[i][j], 0, 0, 0);
        }
        __syncthreads();
    }
    const int lr = lane & 15, lh = lane >> 4;
    u16* Dp = DT + (size_t)sl * SLICE;
    #pragma unroll
    for (int i = 0; i < 4; i++)
        #pragma unroll
        for (int j = 0; j < 4; j++) {
            f32x4 v = acc[i][j];
            #pragma unroll
            for (int r2 = 0; r2 < 4; r2++)
                Dp[(size_t)(wb + wr + i*16 + lh*4 + r2)*CD + wc + j*16 + lr] = f2bf(v[r2]);
        }
}

// ---------------- gc conv MFMA (K=384) + BN + bf16 residual (from Sbf, in place) + BN ----------------
// writes: Sbf bf16 [o][n] (next state, native), SnT bf16 [n][o] (via LDS bounce)
__global__ __launch_bounds__(256) void k_gc_mx(
        const u16* __restrict__ ST, const u16* __restrict__ X1T, const u16* __restrict__ X2T,
        const u16* __restrict__ Wg, const float* __restrict__ bias,
        u16* __restrict__ Sbf, u16* __restrict__ SnT,
        const float* __restrict__ gg, const float* __restrict__ gb,
        const float* __restrict__ gm, const float* __restrict__ gv,
        const float* __restrict__ bg, const float* __restrict__ bb,
        const float* __restrict__ bm, const float* __restrict__ bv){
    __shared__ __align__(16) short AB[2*128*72];   // As|Bs, re-used as Tt[128][136] in epilogue
    __shared__ float Cst[5*128];
    short* As = AB;
    short* Bs = AB + 128*72;
    short* Tt = AB;
    const int t    = threadIdx.x;
    const int sl   = blockIdx.x >> 2;
    const int nb   = (blockIdx.x & 3) * 128;
    const int lane = t & 63, wid = t >> 6;
    const int wr   = (wid >> 1) * 64, wc = (wid & 1) * 64;
    const int r0   = t >> 3, co = (t & 7) * 8;
    if (t < 128) {
        float ig = gg[t] * rsqrtf(gv[t] + 1e-5f);
        float ib = bg[t] * rsqrtf(bv[t] + 1e-5f);
        Cst[t]       = ig;
        Cst[128 + t] = gb[t] - gm[t]*ig;
        Cst[256 + t] = ib;
        Cst[384 + t] = bb[t] - bm[t]*ib;
        Cst[512 + t] = bias[t];
    }
    const u16* srcs[3] = { ST  + (size_t)sl*SLICE,
                           X1T + (size_t)sl*SLICE,
                           X2T + (size_t)sl*SLICE };
    f32x4 acc[4][4] = {};
    #pragma unroll
    for (int kb = 0; kb < 384; kb += 64) {
        const u16* Sp = srcs[kb >> 7];
        const int  kc = kb & 127;
        #pragma unroll
        for (int p = 0; p < 4; p++) {
            int row = p*32 + r0;
            *(short8*)(As + row*72 + co) = *(const short8*)(Wg + (size_t)row*384 + kb + co);
            *(short8*)(Bs + row*72 + co) = *(const short8*)(Sp + (size_t)(nb+row)*CD + kc + co);
        }
        __syncthreads();
        #pragma unroll
        for (int ks = 0; ks < 64; ks += 32) {
            const int kg = ks + ((lane >> 4) << 3);
            const int lr = lane & 15;
            short8 af[4], bfr[4];
            #pragma unroll
            for (int i = 0; i < 4; i++) af[i]  = *(const short8*)(As + (wr + i*16 + lr)*72 + kg);
            #pragma unroll
            for (int j = 0; j < 4; j++) bfr[j] = *(const short8*)(Bs + (wc + j*16 + lr)*72 + kg);
            #pragma unroll
            for (int i = 0; i < 4; i++)
                #pragma unroll
                for (int j = 0; j < 4; j++)
                    acc[i][j] = __builtin_amdgcn_mfma_f32_16x16x32_bf16(af[i], bfr[j], acc[i][j], 0, 0, 0);
        }
        __syncthreads();
    }
    const int lr = lane & 15, lh = lane >> 4;
    const size_t base = (size_t)sl * SLICE;
    #pragma unroll
    for (int i = 0; i < 4; i++)
        #pragma unroll
        for (int j = 0; j < 4; j++) {
            int nl = wc + j*16 + lr;
            f32x4 a = acc[i][j];
            #pragma unroll
            for (int r2 = 0; r2 < 4; r2++) {
                int o = wr + i*16 + lh*4 + r2;
                float ig = Cst[o], cg = Cst[128+o], ib = Cst[256+o];
                float cb_ = Cst[384+o], h0 = Cst[512+o];
                size_t off = base + (size_t)o*NN + nb + nl;
                float res = bf2f(Sbf[off]);              // previous state = residual
                float v = ib*( ig*(a[r2] + h0) + cg + res ) + cb_;
                u16 bv2 = f2bf(v);
                Sbf[off] = bv2;                          // next state, native layout
                Tt[nl*136 + o] = (short)bv2;
            }
        }
    __syncthreads();
    u16* Dp = SnT + base;
    #pragma unroll
    for (int q = 0; q < 8; q++) {
        int id = t + q*256;
        int row = id >> 4, c0 = (id & 15) * 8;
        *(short8*)(Dp + (size_t)(nb + row)*CD + c0) = *(const short8*)(Tt + row*136 + c0);
    }
}

// ---------------- fused skip: out[n][o] = BN_ob( sum_i Wsk_i·S_i + sum_i b_i ) ----------------
__global__ __launch_bounds__(256) void k_skip_fused(
        const u16* __restrict__ S0T, const u16* __restrict__ S1T, const u16* __restrict__ S2T,
        const u16* __restrict__ Wsb, const float* __restrict__ bsk,
        const float* __restrict__ og, const float* __restrict__ obt,
        const float* __restrict__ om, const float* __restrict__ ov,
        float* __restrict__ out, const int s0){
    __shared__ __align__(16) short As[128*72];   // [n 128][k 64 (+8)]
    __shared__ __align__(16) short Bs[128*72];   // [o 128][k 64 (+8)]
    __shared__ float Cst[3*128];
    const int t    = threadIdx.x;
    const int sl   = blockIdx.x >> 2;
    const int nbt  = (blockIdx.x & 3) * 128;
    const int lane = t & 63, wid = t >> 6;
    const int wr   = (wid >> 1) * 64, wc = (wid & 1) * 64;
    const int r0   = t >> 3, co = (t & 7) * 8;
    if (t < 128) {
        float inv = og[t] * rsqrtf(ov[t] + 1e-5f);
        Cst[t]       = inv;
        Cst[128 + t] = obt[t] - om[t]*inv;
        Cst[256 + t] = bsk[t] + bsk[CD + t] + bsk[2*CD + t];
    }
    const u16* srcs[3] = { S0T + (size_t)sl*SLICE,
                           S1T + (size_t)sl*SLICE,
                           S2T + (size_t)sl*SLICE };
    f32x4 acc[4][4] = {};
    #pragma unroll
    for (int kb = 0; kb < 384; kb += 64) {
        const u16* Sp = srcs[kb >> 7];
        const int  ph = kb >> 7;
        const int  kc = kb & 127;
        #pragma unroll
        for (int p = 0; p < 4; p++) {
            int row = p*32 + r0;
            *(short8*)(As + row*72 + co) = *(const short8*)(Sp + (size_t)(nbt+row)*CD + kc + co);
            *(short8*)(Bs + row*72 + co) = *(const short8*)(Wsb + (size_t)ph*CD*CD + (size_t)row*CD + kc + co);
        }
        __syncthreads();
        #pragma unroll
        for (int ks = 0; ks < 64; ks += 32) {
            const int kg = ks + ((lane >> 4) << 3);
            const int lr = lane & 15;
            short8 af[4], bfr[4];
            #pragma unroll
            for (int i = 0; i < 4; i++) af[i]  = *(const short8*)(As + (wr + i*16 + lr)*72 + kg);
            #pragma unroll
            for (int j = 0; j < 4; j++) bfr[j] = *(const short8*)(Bs + (wc + j*16 + lr)*72 + kg);
            #pragma unroll
            for (int i = 0; i < 4; i++)
                #pragma unroll
                for (int j = 0; j < 4; j++)
                    acc[i][j] = __builtin_amdgcn_mfma_f32_16x16x32_bf16(af[i], bfr[j], acc[i][j], 0, 0, 0);
        }
        __syncthreads();
    }
    const int lr = lane & 15, lh = lane >> 4;
    float* Op = out + (size_t)(s0 + sl) * SLICE;
    #pragma unroll
    for (int i = 0; i < 4; i++)
        #pragma unroll
        for (int j = 0; j < 4; j++) {
            int o = wc + j*16 + lr;
            float ao = Cst[o], c0_ = Cst[128+o], sb = Cst[256+o];
            f32x4 v = acc[i][j];
            #pragma unroll
            for (int r2 = 0; r2 < 4; r2++) {
                int n = nbt + wr + i*16 + lh*4 + r2;
                Op[(size_t)n*CD + o] = ao*(v[r2] + sb) + c0_;
            }
        }
}

extern "C" void kernel_launch(void* const* d_in, const int* in_sizes, int n_in,
                              void* d_out, int out_size, void* d_ws, size_t ws_size,
                              hipStream_t stream) {
    const float* x0   = (const float*)d_in[0];
    const float* adj  = (const float*)d_in[1];
    const float* Wst  = (const float*)d_in[2];
    const float* bst  = (const float*)d_in[3];
    const float* Wsk  = (const float*)d_in[4];
    const float* bsk  = (const float*)d_in[5];
    const float* Wgc  = (const float*)d_in[6];
    const float* bgc  = (const float*)d_in[7];
    const float* gg   = (const float*)d_in[8];
    const float* gb   = (const float*)d_in[9];
    const float* gm   = (const float*)d_in[10];
    const float* gv   = (const float*)d_in[11];
    const float* bg   = (const float*)d_in[12];
    const float* bb   = (const float*)d_in[13];
    const float* bm   = (const float*)d_in[14];
    const float* bv   = (const float*)d_in[15];
    const float* og   = (const float*)d_in[16];
    const float* obt  = (const float*)d_in[17];
    const float* om   = (const float*)d_in[18];
    const float* ov   = (const float*)d_in[19];
    float* out = (float*)d_out;            // [s][n][o]

    // ---- workspace layout: globals first, then SC per-slice buffers ----
    float* A2f   = (float*)d_ws;                         // 1 MB
    u16*   AT    = (u16*)(A2f + NN*NN);                  // 512 KB
    u16*   A2T   = AT  + NN*NN;                          // 512 KB
    u16*   Wskbf = A2T + NN*NN;                          // 96 KB
    u16*   Wgcbf = Wskbf + 3*CD*CD;                      // 192 KB
    char*  pend  = (char*)(Wgcbf + 2*CD*384);
    size_t goff  = ((size_t)(pend - (char*)d_ws) + 255) & ~(size_t)255;

    // per-slice: Sbf,S0T,S1T,S2T,X1T,X2T bf16 = 6*128K = 768 KB
    static const int divs[] = {768,384,256,192,128,96,64,48,32,24,16,12,8,6,4,3,2,1};
    const size_t perSlice = 6*(size_t)SLICE*2;
    int SC = 1;
    for (int di = 0; di < 18; di++) {
        if (goff + (size_t)divs[di]*perSlice <= ws_size) { SC = divs[di]; break; }
    }
    u16* Sbf = (u16*)((char*)d_ws + goff);
    u16* S0T = Sbf + (size_t)SC*SLICE;
    u16* S1T = S0T + (size_t)SC*SLICE;
    u16* S2T = S1T + (size_t)SC*SLICE;
    u16* X1T = S2T + (size_t)SC*SLICE;
    u16* X2T = X1T + (size_t)SC*SLICE;

    // ---- one-time precompute ----
    k_adjT<<<(NN*NN)/256, 256, 0, stream>>>(adj, AT);
    k_a2  <<<NN*2,        256, 0, stream>>>(adj, A2f);
    k_adjT<<<(NN*NN)/256, 256, 0, stream>>>(A2f, A2T);
    k_cast<<<(3*CD*CD)/256,  256, 0, stream>>>(Wsk, Wskbf);
    k_cast<<<(2*CD*384)/256, 256, 0, stream>>>(Wgc, Wgcbf);

    for (int s0 = 0; s0 < NSL; s0 += SC) {
        k_start<<<SC*8, 256, 0, stream>>>(x0, Wst, bst, Sbf, S0T, s0);
        for (int i = 0; i < 2; i++) {
            k_hop2<<<SC*8, 256, 0, stream>>>(AT, A2T, Sbf, X1T, X2T);
            k_gc_mx<<<SC*4, 256, 0, stream>>>(
                (i ? S1T : S0T), X1T, X2T,
                Wgcbf + (size_t)i*CD*384, bgc + i*CD,
                Sbf, (i ? S2T : S1T),
                gg + i*CD, gb + i*CD, gm + i*CD, gv + i*CD,
                bg + i*CD, bb + i*CD, bm + i*CD, bv + i*CD);
        }
        k_skip_fused<<<SC*4, 256, 0, stream>>>(S0T, S1T, S2T, Wskbf, bsk,
                                               og, obt, om, ov, out, s0);
    }
}

// Round 4
// 1034.325 us; speedup vs baseline: 4.5717x; 1.1220x over previous
//
#include <hip/hip_runtime.h>

#define TT 12
#define NN 512
#define CD 128
#define SLICE (CD*NN)   // 65536
#define NSL 768         // B*T

typedef __attribute__((ext_vector_type(8))) short short8;   // 8 bf16 (4 VGPRs)
typedef __attribute__((ext_vector_type(4))) float f32x4;    // MFMA C/D
typedef unsigned short u16;

__device__ __forceinline__ u16 f2bf(float f){
    union { float f; unsigned u; } v; v.f = f;
    return (u16)((v.u + 0x7FFFu + ((v.u >> 16) & 1u)) >> 16);   // RNE
}
__device__ __forceinline__ float bf2f(u16 h){
    union { unsigned u; float f; } v; v.u = ((unsigned)h) << 16;
    return v.f;
}

// ---------------- transpose+cast 512x512: DT[w][v] = bf16(src[v][w]) ----------------
__global__ __launch_bounds__(256) void k_adjT(const float* __restrict__ src,
        u16* __restrict__ DT){
    int idx = blockIdx.x*256 + threadIdx.x;          // 512*512
    int w = idx >> 9, v = idx & (NN-1);
    DT[(size_t)w*NN + v] = f2bf(src[(size_t)v*NN + w]);
}

// ---------------- A2[u][w] = sum_v adj[u][v]*adj[v][w] (fp32, once) ----------------
__global__ __launch_bounds__(256) void k_a2(const float* __restrict__ adj,
        float* __restrict__ A2){
    int u = blockIdx.x >> 1;
    int w = (blockIdx.x & 1)*256 + threadIdx.x;
    float acc = 0.f;
    for (int v = 0; v < NN; v++) acc += adj[(size_t)u*NN+v] * adj[(size_t)v*NN+w];
    A2[(size_t)u*NN+w] = acc;
}

// ---------------- generic fp32 -> bf16 cast ----------------
__global__ __launch_bounds__(256) void k_cast(const float* __restrict__ src,
        u16* __restrict__ dst){
    int i = blockIdx.x*256 + threadIdx.x;
    dst[i] = f2bf(src[i]);
}

// ---------------- start conv: Sbf[d][n] bf16 + S0T[n][d] bf16 ----------------
__global__ __launch_bounds__(256) void k_start(const float* __restrict__ x0,
        const float* __restrict__ Wst, const float* __restrict__ bst,
        u16* __restrict__ Sbf, u16* __restrict__ S0T, const int s0){
    __shared__ float Lv[2*64];
    __shared__ __align__(16) short Tt[64*136];       // [n 64][d 128 (+8)]
    const int t  = threadIdx.x;
    const int sl = blockIdx.x >> 3;
    const int n0 = (blockIdx.x & 7) * 64;
    const int s = s0 + sl;
    const int b = s / TT, tt = s - b*TT;
    if (t < 128) {
        int ci = t >> 6, nl2 = t & 63;
        Lv[ci*64 + nl2] = x0[(size_t)((b*2 + ci)*NN + n0 + nl2)*TT + tt];
    }
    __syncthreads();
    const int nl = t & 63;
    const int dg = (t >> 6) * 32;
    const float v0 = Lv[nl], v1 = Lv[64 + nl];
    const size_t base = (size_t)sl * SLICE;
    #pragma unroll 4
    for (int dd = 0; dd < 32; dd++) {
        int d = dg + dd;
        float val = Wst[2*d]*v0 + Wst[2*d+1]*v1 + bst[d];
        u16 bv = f2bf(val);
        Sbf[base + (size_t)d*NN + n0 + nl] = bv;
        Tt[nl*136 + d] = (short)bv;
    }
    __syncthreads();
    #pragma unroll
    for (int q = 0; q < 4; q++) {
        int id = t + q*256;
        int row = id >> 4, c0 = (id & 15) * 8;
        *(short8*)(S0T + base + (size_t)(n0 + row)*CD + c0) =
            *(const short8*)(Tt + row*136 + c0);
    }
}

// ---------------- fused double hop (flipped): D[c][w] = sum_v Sbf[c][v]*M[w][v] ----------------
// M in {AT, A2T}; output X?T[w][c] minor axis = c = D rows -> ushort4 wide stores.
__global__ __launch_bounds__(256) void k_hop2(const u16* __restrict__ AT,
        const u16* __restrict__ A2T, const u16* __restrict__ Sbf,
        u16* __restrict__ X1T, u16* __restrict__ X2T){
    __shared__ __align__(16) short As[128*72];   // [c 128][v 64 (+8)]
    __shared__ __align__(16) short Bs[128*72];   // [w 128][v 64 (+8)]
    const int t    = threadIdx.x;
    const int sl   = blockIdx.x >> 3;
    const int r    = blockIdx.x & 7;
    const u16* M   = (r & 4) ? A2T : AT;
    u16* DT        = (r & 4) ? X2T : X1T;
    const int wb   = (r & 3) * 128;              // w-tile base
    const int lane = t & 63, wid = t >> 6;
    const int wr   = (wid >> 1) * 64, wc = (wid & 1) * 64;  // wr: c-offset, wc: w-offset
    const int r0   = t >> 3, co = (t & 7) * 8;
    const u16* Ss  = Sbf + (size_t)sl * SLICE;
    f32x4 acc[4][4] = {};
    for (int kb = 0; kb < NN; kb += 64) {
        #pragma unroll
        for (int p = 0; p < 4; p++) {
            int row = p*32 + r0;
            *(short8*)(As + row*72 + co) = *(const short8*)(Ss + (size_t)row*NN + kb + co);
            *(short8*)(Bs + row*72 + co) = *(const short8*)(M  + (size_t)(wb+row)*NN + kb + co);
        }
        __syncthreads();
        #pragma unroll
        for (int ks = 0; ks < 64; ks += 32) {
            const int kg = ks + ((lane >> 4) << 3);
            const int lr = lane & 15;
            short8 af[4], bfr[4];
            #pragma unroll
            for (int i = 0; i < 4; i++) af[i]  = *(const short8*)(As + (wr + i*16 + lr)*72 + kg);
            #pragma unroll
            for (int j = 0; j < 4; j++) bfr[j] = *(const short8*)(Bs + (wc + j*16 + lr)*72 + kg);
            #pragma unroll
            for (int i = 0; i < 4; i++)
                #pragma unroll
                for (int j = 0; j < 4; j++)
                    acc[i][j] = __builtin_amdgcn_mfma_f32_16x16x32_bf16(af[i], bfr[j], acc[i][j], 0, 0, 0);
        }
        __syncthreads();
    }
    const int lr = lane & 15, lh = lane >> 4;
    u16* Dp = DT + (size_t)sl * SLICE;
    #pragma unroll
    for (int i = 0; i < 4; i++)
        #pragma unroll
        for (int j = 0; j < 4; j++) {
            const int c0 = wr + i*16 + lh*4;             // D row quad (consecutive c)
            const int w  = wb + wc + j*16 + lr;          // D col (per lane)
            f32x4 v = acc[i][j];
            ushort4 q;
            q.x = f2bf(v[0]); q.y = f2bf(v[1]); q.z = f2bf(v[2]); q.w = f2bf(v[3]);
            *(ushort4*)(Dp + (size_t)w*CD + c0) = q;     // 8B wide store
        }
}

// ---------------- gc conv MFMA (K=384) + BN + residual + BN ----------------
// D rows=o, cols=n. Residual read wide from STprev[n][o]; SnT[n][o] stored wide
// from the register quad; Sbf[o][n] scalar stores (fire-and-forget).
__global__ __launch_bounds__(256) void k_gc_mx(
        const u16* __restrict__ ST, const u16* __restrict__ X1T, const u16* __restrict__ X2T,
        const u16* __restrict__ Wg, const float* __restrict__ bias,
        u16* __restrict__ Sbf, u16* __restrict__ SnT,
        const float* __restrict__ gg, const float* __restrict__ gb,
        const float* __restrict__ gm, const float* __restrict__ gv,
        const float* __restrict__ bg, const float* __restrict__ bb,
        const float* __restrict__ bm, const float* __restrict__ bv){
    __shared__ __align__(16) short As[128*72];   // [o 128][k 64 (+8)]
    __shared__ __align__(16) short Bs[128*72];   // [n 128][k 64 (+8)]
    __shared__ float Cst[5*128];
    const int t    = threadIdx.x;
    const int sl   = blockIdx.x >> 2;
    const int nb   = (blockIdx.x & 3) * 128;
    const int lane = t & 63, wid = t >> 6;
    const int wr   = (wid >> 1) * 64, wc = (wid & 1) * 64;  // wr: o-offset, wc: n-offset
    const int r0   = t >> 3, co = (t & 7) * 8;
    if (t < 128) {
        float ig = gg[t] * rsqrtf(gv[t] + 1e-5f);
        float ib = bg[t] * rsqrtf(bv[t] + 1e-5f);
        Cst[t]       = ig;
        Cst[128 + t] = gb[t] - gm[t]*ig;
        Cst[256 + t] = ib;
        Cst[384 + t] = bb[t] - bm[t]*ib;
        Cst[512 + t] = bias[t];
    }
    const u16* srcs[3] = { ST  + (size_t)sl*SLICE,
                           X1T + (size_t)sl*SLICE,
                           X2T + (size_t)sl*SLICE };
    f32x4 acc[4][4] = {};
    #pragma unroll
    for (int kb = 0; kb < 384; kb += 64) {
        const u16* Sp = srcs[kb >> 7];
        const int  kc = kb & 127;
        #pragma unroll
        for (int p = 0; p < 4; p++) {
            int row = p*32 + r0;
            *(short8*)(As + row*72 + co) = *(const short8*)(Wg + (size_t)row*384 + kb + co);
            *(short8*)(Bs + row*72 + co) = *(const short8*)(Sp + (size_t)(nb+row)*CD + kc + co);
        }
        __syncthreads();
        #pragma unroll
        for (int ks = 0; ks < 64; ks += 32) {
            const int kg = ks + ((lane >> 4) << 3);
            const int lr = lane & 15;
            short8 af[4], bfr[4];
            #pragma unroll
            for (int i = 0; i < 4; i++) af[i]  = *(const short8*)(As + (wr + i*16 + lr)*72 + kg);
            #pragma unroll
            for (int j = 0; j < 4; j++) bfr[j] = *(const short8*)(Bs + (wc + j*16 + lr)*72 + kg);
            #pragma unroll
            for (int i = 0; i < 4; i++)
                #pragma unroll
                for (int j = 0; j < 4; j++)
                    acc[i][j] = __builtin_amdgcn_mfma_f32_16x16x32_bf16(af[i], bfr[j], acc[i][j], 0, 0, 0);
        }
        __syncthreads();
    }
    const int lr = lane & 15, lh = lane >> 4;
    const size_t base = (size_t)sl * SLICE;
    const u16* Rs = srcs[0];                     // previous state, [n][o] layout
    u16* Sn = SnT + base;
    #pragma unroll
    for (int i = 0; i < 4; i++) {
        const int o0 = wr + i*16 + lh*4;         // D row quad (consecutive o)
        float ig4[4], cg4[4], ib4[4], cb4[4], h04[4];
        #pragma unroll
        for (int r2 = 0; r2 < 4; r2++) {
            int o = o0 + r2;
            ig4[r2] = Cst[o]; cg4[r2] = Cst[128+o]; ib4[r2] = Cst[256+o];
            cb4[r2] = Cst[384+o]; h04[r2] = Cst[512+o];
        }
        #pragma unroll
        for (int j = 0; j < 4; j++) {
            const int nl = wc + j*16 + lr;       // D col (per lane)
            ushort4 r4 = *(const ushort4*)(Rs + (size_t)(nb + nl)*CD + o0);
            f32x4 a = acc[i][j];
            u16 bq[4];
            bq[0] = f2bf(ib4[0]*( ig4[0]*(a[0] + h04[0]) + cg4[0] + bf2f(r4.x) ) + cb4[0]);
            bq[1] = f2bf(ib4[1]*( ig4[1]*(a[1] + h04[1]) + cg4[1] + bf2f(r4.y) ) + cb4[1]);
            bq[2] = f2bf(ib4[2]*( ig4[2]*(a[2] + h04[2]) + cg4[2] + bf2f(r4.z) ) + cb4[2]);
            bq[3] = f2bf(ib4[3]*( ig4[3]*(a[3] + h04[3]) + cg4[3] + bf2f(r4.w) ) + cb4[3]);
            ushort4 q; q.x = bq[0]; q.y = bq[1]; q.z = bq[2]; q.w = bq[3];
            *(ushort4*)(Sn + (size_t)(nb + nl)*CD + o0) = q;   // 8B wide store
            #pragma unroll
            for (int r2 = 0; r2 < 4; r2++)
                Sbf[base + (size_t)(o0 + r2)*NN + nb + nl] = bq[r2];
        }
    }
}

// ---------------- fused skip (flipped): D[o][n] = sum W[o][k]*S[n][k]; float4 out stores ----------------
__global__ __launch_bounds__(256) void k_skip_fused(
        const u16* __restrict__ S0T, const u16* __restrict__ S1T, const u16* __restrict__ S2T,
        const u16* __restrict__ Wsb, const float* __restrict__ bsk,
        const float* __restrict__ og, const float* __restrict__ obt,
        const float* __restrict__ om, const float* __restrict__ ov,
        float* __restrict__ out, const int s0){
    __shared__ __align__(16) short As[128*72];   // [o 128][k 64 (+8)]
    __shared__ __align__(16) short Bs[128*72];   // [n 128][k 64 (+8)]
    __shared__ float Cst[3*128];
    const int t    = threadIdx.x;
    const int sl   = blockIdx.x >> 2;
    const int nbt  = (blockIdx.x & 3) * 128;
    const int lane = t & 63, wid = t >> 6;
    const int wr   = (wid >> 1) * 64, wc = (wid & 1) * 64;  // wr: o-offset, wc: n-offset
    const int r0   = t >> 3, co = (t & 7) * 8;
    if (t < 128) {
        float inv = og[t] * rsqrtf(ov[t] + 1e-5f);
        Cst[t]       = inv;
        Cst[128 + t] = obt[t] - om[t]*inv;
        Cst[256 + t] = bsk[t] + bsk[CD + t] + bsk[2*CD + t];
    }
    const u16* srcs[3] = { S0T + (size_t)sl*SLICE,
                           S1T + (size_t)sl*SLICE,
                           S2T + (size_t)sl*SLICE };
    f32x4 acc[4][4] = {};
    #pragma unroll
    for (int kb = 0; kb < 384; kb += 64) {
        const u16* Sp = srcs[kb >> 7];
        const int  ph = kb >> 7;
        const int  kc = kb & 127;
        #pragma unroll
        for (int p = 0; p < 4; p++) {
            int row = p*32 + r0;
            *(short8*)(As + row*72 + co) = *(const short8*)(Wsb + (size_t)ph*CD*CD + (size_t)row*CD + kc + co);
            *(short8*)(Bs + row*72 + co) = *(const short8*)(Sp + (size_t)(nbt+row)*CD + kc + co);
        }
        __syncthreads();
        #pragma unroll
        for (int ks = 0; ks < 64; ks += 32) {
            const int kg = ks + ((lane >> 4) << 3);
            const int lr = lane & 15;
            short8 af[4], bfr[4];
            #pragma unroll
            for (int i = 0; i < 4; i++) af[i]  = *(const short8*)(As + (wr + i*16 + lr)*72 + kg);
            #pragma unroll
            for (int j = 0; j < 4; j++) bfr[j] = *(const short8*)(Bs + (wc + j*16 + lr)*72 + kg);
            #pragma unroll
            for (int i = 0; i < 4; i++)
                #pragma unroll
                for (int j = 0; j < 4; j++)
                    acc[i][j] = __builtin_amdgcn_mfma_f32_16x16x32_bf16(af[i], bfr[j], acc[i][j], 0, 0, 0);
        }
        __syncthreads();
    }
    const int lr = lane & 15, lh = lane >> 4;
    float* Op = out + (size_t)(s0 + sl) * SLICE;
    #pragma unroll
    for (int i = 0; i < 4; i++) {
        const int o0 = wr + i*16 + lh*4;         // D row quad (consecutive o)
        float ao4[4], c04[4], sb4[4];
        #pragma unroll
        for (int r2 = 0; r2 < 4; r2++) {
            int o = o0 + r2;
            ao4[r2] = Cst[o]; c04[r2] = Cst[128+o]; sb4[r2] = Cst[256+o];
        }
        #pragma unroll
        for (int j = 0; j < 4; j++) {
            const int n = nbt + wc + j*16 + lr;  // D col (per lane)
            f32x4 v = acc[i][j];
            float4 q;
            q.x = ao4[0]*(v[0] + sb4[0]) + c04[0];
            q.y = ao4[1]*(v[1] + sb4[1]) + c04[1];
            q.z = ao4[2]*(v[2] + sb4[2]) + c04[2];
            q.w = ao4[3]*(v[3] + sb4[3]) + c04[3];
            *(float4*)(Op + (size_t)n*CD + o0) = q;    // 16B wide store
        }
    }
}

extern "C" void kernel_launch(void* const* d_in, const int* in_sizes, int n_in,
                              void* d_out, int out_size, void* d_ws, size_t ws_size,
                              hipStream_t stream) {
    const float* x0   = (const float*)d_in[0];
    const float* adj  = (const float*)d_in[1];
    const float* Wst  = (const float*)d_in[2];
    const float* bst  = (const float*)d_in[3];
    const float* Wsk  = (const float*)d_in[4];
    const float* bsk  = (const float*)d_in[5];
    const float* Wgc  = (const float*)d_in[6];
    const float* bgc  = (const float*)d_in[7];
    const float* gg   = (const float*)d_in[8];
    const float* gb   = (const float*)d_in[9];
    const float* gm   = (const float*)d_in[10];
    const float* gv   = (const float*)d_in[11];
    const float* bg   = (const float*)d_in[12];
    const float* bb   = (const float*)d_in[13];
    const float* bm   = (const float*)d_in[14];
    const float* bv   = (const float*)d_in[15];
    const float* og   = (const float*)d_in[16];
    const float* obt  = (const float*)d_in[17];
    const float* om   = (const float*)d_in[18];
    const float* ov   = (const float*)d_in[19];
    float* out = (float*)d_out;            // [s][n][o]

    // ---- workspace layout: globals first, then SC per-slice buffers ----
    float* A2f   = (float*)d_ws;                         // 1 MB
    u16*   AT    = (u16*)(A2f + NN*NN);                  // 512 KB
    u16*   A2T   = AT  + NN*NN;                          // 512 KB
    u16*   Wskbf = A2T + NN*NN;                          // 96 KB
    u16*   Wgcbf = Wskbf + 3*CD*CD;                      // 192 KB
    char*  pend  = (char*)(Wgcbf + 2*CD*384);
    size_t goff  = ((size_t)(pend - (char*)d_ws) + 255) & ~(size_t)255;

    // per-slice: Sbf,S0T,S1T,S2T,X1T,X2T bf16 = 6*128K = 768 KB
    static const int divs[] = {768,384,256,192,128,96,64,48,32,24,16,12,8,6,4,3,2,1};
    const size_t perSlice = 6*(size_t)SLICE*2;
    int SC = 1;
    for (int di = 0; di < 18; di++) {
        if (goff + (size_t)divs[di]*perSlice <= ws_size) { SC = divs[di]; break; }
    }
    u16* Sbf = (u16*)((char*)d_ws + goff);
    u16* S0T = Sbf + (size_t)SC*SLICE;
    u16* S1T = S0T + (size_t)SC*SLICE;
    u16* S2T = S1T + (size_t)SC*SLICE;
    u16* X1T = S2T + (size_t)SC*SLICE;
    u16* X2T = X1T + (size_t)SC*SLICE;

    // ---- one-time precompute ----
    k_adjT<<<(NN*NN)/256, 256, 0, stream>>>(adj, AT);
    k_a2  <<<NN*2,        256, 0, stream>>>(adj, A2f);
    k_adjT<<<(NN*NN)/256, 256, 0, stream>>>(A2f, A2T);
    k_cast<<<(3*CD*CD)/256,  256, 0, stream>>>(Wsk, Wskbf);
    k_cast<<<(2*CD*384)/256, 256, 0, stream>>>(Wgc, Wgcbf);

    for (int s0 = 0; s0 < NSL; s0 += SC) {
        k_start<<<SC*8, 256, 0, stream>>>(x0, Wst, bst, Sbf, S0T, s0);
        for (int i = 0; i < 2; i++) {
            k_hop2<<<SC*8, 256, 0, stream>>>(AT, A2T, Sbf, X1T, X2T);
            k_gc_mx<<<SC*4, 256, 0, stream>>>(
                (i ? S1T : S0T), X1T, X2T,
                Wgcbf + (size_t)i*CD*384, bgc + i*CD,
                Sbf, (i ? S2T : S1T),
                gg + i*CD, gb + i*CD, gm + i*CD, gv + i*CD,
                bg + i*CD, bb + i*CD, bm + i*CD, bv + i*CD);
        }
        k_skip_fused<<<SC*4, 256, 0, stream>>>(S0T, S1T, S2T, Wskbf, bsk,
                                               og, obt, om, ov, out, s0);
    }
}

// Round 5
// 988.156 us; speedup vs baseline: 4.7853x; 1.0467x over previous
//
#include <hip/hip_runtime.h>

#define TT 12
#define NN 512
#define CD 128
#define SLICE (CD*NN)   // 65536
#define NSL 768         // B*T

typedef __attribute__((ext_vector_type(8))) short short8;   // 8 bf16 (4 VGPRs)
typedef __attribute__((ext_vector_type(4))) float f32x4;    // MFMA C/D
typedef unsigned short u16;

__device__ __forceinline__ u16 f2bf(float f){
    union { float f; unsigned u; } v; v.f = f;
    return (u16)((v.u + 0x7FFFu + ((v.u >> 16) & 1u)) >> 16);   // RNE
}
__device__ __forceinline__ float bf2f(u16 h){
    union { unsigned u; float f; } v; v.u = ((unsigned)h) << 16;
    return v.f;
}

// ---- async global->LDS, 16B per lane (dest = wave-uniform base + lane*16) ----
__device__ __forceinline__ void gload16(const void* g, void* l){
    __builtin_amdgcn_global_load_lds(
        (const __attribute__((address_space(1))) unsigned int*)g,
        (__attribute__((address_space(3))) unsigned int*)l, 16, 0, 0);
}

// Stage a [128 rows][64 shorts] tile from global (rowstride bytes) into LDS.
// LDS dest is LINEAR (row*128B + col); the global SOURCE column is pre-swizzled
// (col ^= ((row&7)<<4) bytes) so that swizzled ds_reads are conflict-free.
// gbase must already include the k-column byte offset.
__device__ __forceinline__ void stage128x64(short* lds, const char* gbase,
        const int rowstride, const int t){
    const int rr  = t >> 3;                          // row-in-32 (0..31)
    const int swz = (((t & 7) ^ (rr & 7)) << 4);     // swizzled 16B slot in 128B row
    short* lw = lds + ((t >> 6) << 9);               // wave base: (t>>6)*8 rows * 64
    #pragma unroll
    for (int p = 0; p < 4; p++){
        gload16(gbase + (size_t)(p*32 + rr)*rowstride + swz, lw + p*2048);
    }
}

// ---------------- transpose+cast 512x512: DT[w][v] = bf16(src[v][w]) ----------------
__global__ __launch_bounds__(256) void k_adjT(const float* __restrict__ src,
        u16* __restrict__ DT){
    int idx = blockIdx.x*256 + threadIdx.x;          // 512*512
    int w = idx >> 9, v = idx & (NN-1);
    DT[(size_t)w*NN + v] = f2bf(src[(size_t)v*NN + w]);
}

// ---------------- A2[u][w] = sum_v adj[u][v]*adj[v][w] (fp32, once) ----------------
__global__ __launch_bounds__(256) void k_a2(const float* __restrict__ adj,
        float* __restrict__ A2){
    int u = blockIdx.x >> 1;
    int w = (blockIdx.x & 1)*256 + threadIdx.x;
    float acc = 0.f;
    for (int v = 0; v < NN; v++) acc += adj[(size_t)u*NN+v] * adj[(size_t)v*NN+w];
    A2[(size_t)u*NN+w] = acc;
}

// ---------------- generic fp32 -> bf16 cast ----------------
__global__ __launch_bounds__(256) void k_cast(const float* __restrict__ src,
        u16* __restrict__ dst){
    int i = blockIdx.x*256 + threadIdx.x;
    dst[i] = f2bf(src[i]);
}

// ---------------- start conv: Sbf[d][n] bf16 + S0T[n][d] bf16 ----------------
__global__ __launch_bounds__(256) void k_start(const float* __restrict__ x0,
        const float* __restrict__ Wst, const float* __restrict__ bst,
        u16* __restrict__ Sbf, u16* __restrict__ S0T, const int s0){
    __shared__ float Lv[2*64];
    __shared__ __align__(16) short Tt[64*136];       // [n 64][d 128 (+8)]
    const int t  = threadIdx.x;
    const int sl = blockIdx.x >> 3;
    const int n0 = (blockIdx.x & 7) * 64;
    const int s = s0 + sl;
    const int b = s / TT, tt = s - b*TT;
    if (t < 128) {
        int ci = t >> 6, nl2 = t & 63;
        Lv[ci*64 + nl2] = x0[(size_t)((b*2 + ci)*NN + n0 + nl2)*TT + tt];
    }
    __syncthreads();
    const int nl = t & 63;
    const int dg = (t >> 6) * 32;
    const float v0 = Lv[nl], v1 = Lv[64 + nl];
    const size_t base = (size_t)sl * SLICE;
    #pragma unroll 4
    for (int dd = 0; dd < 32; dd++) {
        int d = dg + dd;
        float val = Wst[2*d]*v0 + Wst[2*d+1]*v1 + bst[d];
        u16 bv = f2bf(val);
        Sbf[base + (size_t)d*NN + n0 + nl] = bv;
        Tt[nl*136 + d] = (short)bv;
    }
    __syncthreads();
    #pragma unroll
    for (int q = 0; q < 4; q++) {
        int id = t + q*256;
        int row = id >> 4, c0 = (id & 15) * 8;
        *(short8*)(S0T + base + (size_t)(n0 + row)*CD + c0) =
            *(const short8*)(Tt + row*136 + c0);
    }
}

// ---------------- fused double hop: D[c][w] = sum_v Sbf[c][v]*M[w][v] ----------------
// M in {AT, A2T}; output X?T[w][c] minor axis = c = D rows -> ushort4 wide stores.
// XCD-swizzled work remap: all 8 blocks of a slice land on one XCD (L2 reuse of Sbf).
__global__ __launch_bounds__(256) void k_hop2(const u16* __restrict__ AT,
        const u16* __restrict__ A2T, const u16* __restrict__ Sbf,
        u16* __restrict__ X1T, u16* __restrict__ X2T){
    __shared__ __align__(16) short As[128*64];   // [c 128][v 64] linear, src-swizzled
    __shared__ __align__(16) short Bs[128*64];   // [w 128][v 64]
    const int t = threadIdx.x;
    int work = blockIdx.x;
    const int nblk = gridDim.x;
    if (!(nblk & 7)) work = (work & 7) * (nblk >> 3) + (work >> 3);
    const int sl = work >> 3;
    const int r  = work & 7;
    const u16* M = (r & 4) ? A2T : AT;
    u16* DT      = (r & 4) ? X2T : X1T;
    const int wb = (r & 3) * 128;                // w-tile base
    const int lane = t & 63, wid = t >> 6;
    const int wr   = (wid >> 1) * 64, wc = (wid & 1) * 64;  // wr: c, wc: w
    const u16* Ss  = Sbf + (size_t)sl * SLICE;
    const int lr = lane & 15;
    const int kh = (lane >> 4) << 3;             // k-group base (shorts)
    const int xr = (lr & 7) << 3;                // read swizzle (shorts)
    f32x4 acc[4][4] = {};
    for (int kb = 0; kb < NN; kb += 64) {
        stage128x64(As, (const char*)Ss + (size_t)kb*2, NN*2, t);
        stage128x64(Bs, (const char*)(M + (size_t)wb*NN) + (size_t)kb*2, NN*2, t);
        __syncthreads();
        #pragma unroll
        for (int ks = 0; ks < 64; ks += 32) {
            const int kx = (ks + kh) ^ xr;
            short8 af[4], bfr[4];
            #pragma unroll
            for (int i = 0; i < 4; i++) af[i]  = *(const short8*)(As + (wr + i*16 + lr)*64 + kx);
            #pragma unroll
            for (int j = 0; j < 4; j++) bfr[j] = *(const short8*)(Bs + (wc + j*16 + lr)*64 + kx);
            #pragma unroll
            for (int i = 0; i < 4; i++)
                #pragma unroll
                for (int j = 0; j < 4; j++)
                    acc[i][j] = __builtin_amdgcn_mfma_f32_16x16x32_bf16(af[i], bfr[j], acc[i][j], 0, 0, 0);
        }
        __syncthreads();
    }
    const int lh = lane >> 4;
    u16* Dp = DT + (size_t)sl * SLICE;
    #pragma unroll
    for (int i = 0; i < 4; i++)
        #pragma unroll
        for (int j = 0; j < 4; j++) {
            const int c0 = wr + i*16 + lh*4;             // D row quad (consecutive c)
            const int w  = wb + wc + j*16 + lr;          // D col (per lane)
            f32x4 v = acc[i][j];
            ushort4 q;
            q.x = f2bf(v[0]); q.y = f2bf(v[1]); q.z = f2bf(v[2]); q.w = f2bf(v[3]);
            *(ushort4*)(Dp + (size_t)w*CD + c0) = q;     // 8B wide store
        }
}

// ---------------- gc conv MFMA (K=384) + BN + residual + BN ----------------
// D rows=o, cols=n. Residual read wide from STprev[n][o]; SnT[n][o] stored wide;
// Sbf[o][n] scalar stores (fire-and-forget).
__global__ __launch_bounds__(256) void k_gc_mx(
        const u16* __restrict__ ST, const u16* __restrict__ X1T, const u16* __restrict__ X2T,
        const u16* __restrict__ Wg, const float* __restrict__ bias,
        u16* __restrict__ Sbf, u16* __restrict__ SnT,
        const float* __restrict__ gg, const float* __restrict__ gb,
        const float* __restrict__ gm, const float* __restrict__ gv,
        const float* __restrict__ bg, const float* __restrict__ bb,
        const float* __restrict__ bm, const float* __restrict__ bv){
    __shared__ __align__(16) short As[128*64];   // [o 128][k 64]
    __shared__ __align__(16) short Bs[128*64];   // [n 128][k 64]
    __shared__ float Cst[5*128];
    const int t    = threadIdx.x;
    const int sl   = blockIdx.x >> 2;
    const int nb   = (blockIdx.x & 3) * 128;
    const int lane = t & 63, wid = t >> 6;
    const int wr   = (wid >> 1) * 64, wc = (wid & 1) * 64;  // wr: o, wc: n
    if (t < 128) {
        float ig = gg[t] * rsqrtf(gv[t] + 1e-5f);
        float ib = bg[t] * rsqrtf(bv[t] + 1e-5f);
        Cst[t]       = ig;
        Cst[128 + t] = gb[t] - gm[t]*ig;
        Cst[256 + t] = ib;
        Cst[384 + t] = bb[t] - bm[t]*ib;
        Cst[512 + t] = bias[t];
    }
    const u16* srcs[3] = { ST  + (size_t)sl*SLICE,
                           X1T + (size_t)sl*SLICE,
                           X2T + (size_t)sl*SLICE };
    const int lr = lane & 15;
    const int kh = (lane >> 4) << 3;
    const int xr = (lr & 7) << 3;
    f32x4 acc[4][4] = {};
    #pragma unroll
    for (int kb = 0; kb < 384; kb += 64) {
        const u16* Sp = srcs[kb >> 7];
        const int  kc = kb & 127;
        stage128x64(As, (const char*)Wg + (size_t)kb*2, 384*2, t);
        stage128x64(Bs, (const char*)(Sp + (size_t)nb*CD) + (size_t)kc*2, CD*2, t);
        __syncthreads();
        #pragma unroll
        for (int ks = 0; ks < 64; ks += 32) {
            const int kx = (ks + kh) ^ xr;
            short8 af[4], bfr[4];
            #pragma unroll
            for (int i = 0; i < 4; i++) af[i]  = *(const short8*)(As + (wr + i*16 + lr)*64 + kx);
            #pragma unroll
            for (int j = 0; j < 4; j++) bfr[j] = *(const short8*)(Bs + (wc + j*16 + lr)*64 + kx);
            #pragma unroll
            for (int i = 0; i < 4; i++)
                #pragma unroll
                for (int j = 0; j < 4; j++)
                    acc[i][j] = __builtin_amdgcn_mfma_f32_16x16x32_bf16(af[i], bfr[j], acc[i][j], 0, 0, 0);
        }
        __syncthreads();
    }
    const int lh = lane >> 4;
    const size_t base = (size_t)sl * SLICE;
    const u16* Rs = srcs[0];                     // previous state, [n][o] layout
    u16* Sn = SnT + base;
    #pragma unroll
    for (int i = 0; i < 4; i++) {
        const int o0 = wr + i*16 + lh*4;         // D row quad (consecutive o)
        float ig4[4], cg4[4], ib4[4], cb4[4], h04[4];
        #pragma unroll
        for (int r2 = 0; r2 < 4; r2++) {
            int o = o0 + r2;
            ig4[r2] = Cst[o]; cg4[r2] = Cst[128+o]; ib4[r2] = Cst[256+o];
            cb4[r2] = Cst[384+o]; h04[r2] = Cst[512+o];
        }
        #pragma unroll
        for (int j = 0; j < 4; j++) {
            const int nl = wc + j*16 + lr;       // D col (per lane)
            ushort4 r4 = *(const ushort4*)(Rs + (size_t)(nb + nl)*CD + o0);
            f32x4 a = acc[i][j];
            u16 bq[4];
            bq[0] = f2bf(ib4[0]*( ig4[0]*(a[0] + h04[0]) + cg4[0] + bf2f(r4.x) ) + cb4[0]);
            bq[1] = f2bf(ib4[1]*( ig4[1]*(a[1] + h04[1]) + cg4[1] + bf2f(r4.y) ) + cb4[1]);
            bq[2] = f2bf(ib4[2]*( ig4[2]*(a[2] + h04[2]) + cg4[2] + bf2f(r4.z) ) + cb4[2]);
            bq[3] = f2bf(ib4[3]*( ig4[3]*(a[3] + h04[3]) + cg4[3] + bf2f(r4.w) ) + cb4[3]);
            ushort4 q; q.x = bq[0]; q.y = bq[1]; q.z = bq[2]; q.w = bq[3];
            *(ushort4*)(Sn + (size_t)(nb + nl)*CD + o0) = q;   // 8B wide store
            #pragma unroll
            for (int r2 = 0; r2 < 4; r2++)
                Sbf[base + (size_t)(o0 + r2)*NN + nb + nl] = bq[r2];
        }
    }
}

// ---------------- fused skip: D[o][n] = sum W[o][k]*S[n][k]; float4 out stores ----------------
__global__ __launch_bounds__(256) void k_skip_fused(
        const u16* __restrict__ S0T, const u16* __restrict__ S1T, const u16* __restrict__ S2T,
        const u16* __restrict__ Wsb, const float* __restrict__ bsk,
        const float* __restrict__ og, const float* __restrict__ obt,
        const float* __restrict__ om, const float* __restrict__ ov,
        float* __restrict__ out, const int s0){
    __shared__ __align__(16) short As[128*64];   // [o 128][k 64]
    __shared__ __align__(16) short Bs[128*64];   // [n 128][k 64]
    __shared__ float Cst[3*128];
    const int t    = threadIdx.x;
    const int sl   = blockIdx.x >> 2;
    const int nbt  = (blockIdx.x & 3) * 128;
    const int lane = t & 63, wid = t >> 6;
    const int wr   = (wid >> 1) * 64, wc = (wid & 1) * 64;  // wr: o, wc: n
    if (t < 128) {
        float inv = og[t] * rsqrtf(ov[t] + 1e-5f);
        Cst[t]       = inv;
        Cst[128 + t] = obt[t] - om[t]*inv;
        Cst[256 + t] = bsk[t] + bsk[CD + t] + bsk[2*CD + t];
    }
    const u16* srcs[3] = { S0T + (size_t)sl*SLICE,
                           S1T + (size_t)sl*SLICE,
                           S2T + (size_t)sl*SLICE };
    const int lr = lane & 15;
    const int kh = (lane >> 4) << 3;
    const int xr = (lr & 7) << 3;
    f32x4 acc[4][4] = {};
    #pragma unroll
    for (int kb = 0; kb < 384; kb += 64) {
        const u16* Sp = srcs[kb >> 7];
        const int  ph = kb >> 7;
        const int  kc = kb & 127;
        stage128x64(As, (const char*)(Wsb + (size_t)ph*CD*CD) + (size_t)kc*2, CD*2, t);
        stage128x64(Bs, (const char*)(Sp + (size_t)nbt*CD) + (size_t)kc*2, CD*2, t);
        __syncthreads();
        #pragma unroll
        for (int ks = 0; ks < 64; ks += 32) {
            const int kx = (ks + kh) ^ xr;
            short8 af[4], bfr[4];
            #pragma unroll
            for (int i = 0; i < 4; i++) af[i]  = *(const short8*)(As + (wr + i*16 + lr)*64 + kx);
            #pragma unroll
            for (int j = 0; j < 4; j++) bfr[j] = *(const short8*)(Bs + (wc + j*16 + lr)*64 + kx);
            #pragma unroll
            for (int i = 0; i < 4; i++)
                #pragma unroll
                for (int j = 0; j < 4; j++)
                    acc[i][j] = __builtin_amdgcn_mfma_f32_16x16x32_bf16(af[i], bfr[j], acc[i][j], 0, 0, 0);
        }
        __syncthreads();
    }
    const int lh = lane >> 4;
    float* Op = out + (size_t)(s0 + sl) * SLICE;
    #pragma unroll
    for (int i = 0; i < 4; i++) {
        const int o0 = wr + i*16 + lh*4;         // D row quad (consecutive o)
        float ao4[4], c04[4], sb4[4];
        #pragma unroll
        for (int r2 = 0; r2 < 4; r2++) {
            int o = o0 + r2;
            ao4[r2] = Cst[o]; c04[r2] = Cst[128+o]; sb4[r2] = Cst[256+o];
        }
        #pragma unroll
        for (int j = 0; j < 4; j++) {
            const int n = nbt + wc + j*16 + lr;  // D col (per lane)
            f32x4 v = acc[i][j];
            float4 q;
            q.x = ao4[0]*(v[0] + sb4[0]) + c04[0];
            q.y = ao4[1]*(v[1] + sb4[1]) + c04[1];
            q.z = ao4[2]*(v[2] + sb4[2]) + c04[2];
            q.w = ao4[3]*(v[3] + sb4[3]) + c04[3];
            *(float4*)(Op + (size_t)n*CD + o0) = q;    // 16B wide store
        }
    }
}

extern "C" void kernel_launch(void* const* d_in, const int* in_sizes, int n_in,
                              void* d_out, int out_size, void* d_ws, size_t ws_size,
                              hipStream_t stream) {
    const float* x0   = (const float*)d_in[0];
    const float* adj  = (const float*)d_in[1];
    const float* Wst  = (const float*)d_in[2];
    const float* bst  = (const float*)d_in[3];
    const float* Wsk  = (const float*)d_in[4];
    const float* bsk  = (const float*)d_in[5];
    const float* Wgc  = (const float*)d_in[6];
    const float* bgc  = (const float*)d_in[7];
    const float* gg   = (const float*)d_in[8];
    const float* gb   = (const float*)d_in[9];
    const float* gm   = (const float*)d_in[10];
    const float* gv   = (const float*)d_in[11];
    const float* bg   = (const float*)d_in[12];
    const float* bb   = (const float*)d_in[13];
    const float* bm   = (const float*)d_in[14];
    const float* bv   = (const float*)d_in[15];
    const float* og   = (const float*)d_in[16];
    const float* obt  = (const float*)d_in[17];
    const float* om   = (const float*)d_in[18];
    const float* ov   = (const float*)d_in[19];
    float* out = (float*)d_out;            // [s][n][o]

    // ---- workspace layout: globals first, then SC per-slice buffers ----
    float* A2f   = (float*)d_ws;                         // 1 MB
    u16*   AT    = (u16*)(A2f + NN*NN);                  // 512 KB
    u16*   A2T   = AT  + NN*NN;                          // 512 KB
    u16*   Wskbf = A2T + NN*NN;                          // 96 KB
    u16*   Wgcbf = Wskbf + 3*CD*CD;                      // 192 KB
    char*  pend  = (char*)(Wgcbf + 2*CD*384);
    size_t goff  = ((size_t)(pend - (char*)d_ws) + 255) & ~(size_t)255;

    // per-slice: Sbf,S0T,S1T,S2T,X1T,X2T bf16 = 6*128K = 768 KB
    static const int divs[] = {768,384,256,192,128,96,64,48,32,24,16,12,8,6,4,3,2,1};
    const size_t perSlice = 6*(size_t)SLICE*2;
    int SC = 1;
    for (int di = 0; di < 18; di++) {
        if (goff + (size_t)divs[di]*perSlice <= ws_size) { SC = divs[di]; break; }
    }
    u16* Sbf = (u16*)((char*)d_ws + goff);
    u16* S0T = Sbf + (size_t)SC*SLICE;
    u16* S1T = S0T + (size_t)SC*SLICE;
    u16* S2T = S1T + (size_t)SC*SLICE;
    u16* X1T = S2T + (size_t)SC*SLICE;
    u16* X2T = X1T + (size_t)SC*SLICE;

    // ---- one-time precompute ----
    k_adjT<<<(NN*NN)/256, 256, 0, stream>>>(adj, AT);
    k_a2  <<<NN*2,        256, 0, stream>>>(adj, A2f);
    k_adjT<<<(NN*NN)/256, 256, 0, stream>>>(A2f, A2T);
    k_cast<<<(3*CD*CD)/256,  256, 0, stream>>>(Wsk, Wskbf);
    k_cast<<<(2*CD*384)/256, 256, 0, stream>>>(Wgc, Wgcbf);

    for (int s0 = 0; s0 < NSL; s0 += SC) {
        k_start<<<SC*8, 256, 0, stream>>>(x0, Wst, bst, Sbf, S0T, s0);
        for (int i = 0; i < 2; i++) {
            k_hop2<<<SC*8, 256, 0, stream>>>(AT, A2T, Sbf, X1T, X2T);
            k_gc_mx<<<SC*4, 256, 0, stream>>>(
                (i ? S1T : S0T), X1T, X2T,
                Wgcbf + (size_t)i*CD*384, bgc + i*CD,
                Sbf, (i ? S2T : S1T),
                gg + i*CD, gb + i*CD, gm + i*CD, gv + i*CD,
                bg + i*CD, bb + i*CD, bm + i*CD, bv + i*CD);
        }
        k_skip_fused<<<SC*4, 256, 0, stream>>>(S0T, S1T, S2T, Wskbf, bsk,
                                               og, obt, om, ov, out, s0);
    }
}

// Round 6
// 860.826 us; speedup vs baseline: 5.4932x; 1.1479x over previous
//
#include <hip/hip_runtime.h>

#define TT 12
#define NN 512
#define CD 128
#define SLICE (CD*NN)   // 65536
#define NSL 768         // B*T

// The whole network is affine (eval-mode BN, no activations):
//   out[s] = sum_{p=0..4} F_p · (x0[s]·A^p) + sum_p q_p · r_p^T
// F_p [128x2], q_p [128], r_p = 1^T A^p [512]. Everything fp32.

// ---------------- prep1: G/H = BN-folded gc weights ----------------
// G_m[o][c] = Db_i[o]*(Dg_i[o]*Wgc[i][o][part*128+c] + (part==0 && o==c))
__global__ __launch_bounds__(256) void k_prep1(const float* __restrict__ Wgc,
        const float* __restrict__ gg, const float* __restrict__ gb,
        const float* __restrict__ gm, const float* __restrict__ gv,
        const float* __restrict__ bg, const float* __restrict__ bb,
        const float* __restrict__ bm, const float* __restrict__ bv,
        float* __restrict__ Gbuf){
    int idx = blockIdx.x*256 + threadIdx.x;          // 6*16384
    int m = idx >> 14, oc = idx & 16383, o = oc >> 7, c = oc & 127;
    int i = (m >= 3) ? 1 : 0, part = m - i*3;
    float Dg = gg[i*CD+o]*rsqrtf(gv[i*CD+o]+1e-5f);
    float Db = bg[i*CD+o]*rsqrtf(bv[i*CD+o]+1e-5f);
    float w = Wgc[(size_t)i*CD*384 + (size_t)o*384 + part*128 + c];
    Gbuf[idx] = Db*(Dg*w + ((part==0 && o==c) ? 1.f : 0.f));
}

// ---------------- prep2: C_p = sum_{a+b=p} H_a·G_b  (S2 coefficients) ----------------
__global__ __launch_bounds__(256) void k_prep2(const float* __restrict__ Gbuf,
        float* __restrict__ Cbuf){
    int p = blockIdx.x >> 2, rg = blockIdx.x & 3;
    int t = threadIdx.x;
    int o = rg*32 + (t>>3), c0 = (t&7)*16;
    float acc[16];
    #pragma unroll
    for (int cc=0; cc<16; cc++) acc[cc] = 0.f;
    int alo = (p > 2) ? p-2 : 0, ahi = (p < 2) ? p : 2;
    for (int a = alo; a <= ahi; a++){
        int b = p - a;
        const float* H = Gbuf + (size_t)(3+a)*16384;
        const float* G = Gbuf + (size_t)b*16384;
        for (int k = 0; k < 128; k++){
            float h = H[o*128+k];
            const float* gr = G + k*128 + c0;
            #pragma unroll
            for (int cc=0; cc<16; cc++) acc[cc] += h*gr[cc];
        }
    }
    float* C = Cbuf + (size_t)p*16384 + o*128 + c0;
    #pragma unroll
    for (int cc=0; cc<16; cc++) C[cc] = acc[cc];
}

// ---------------- prep3: E_p -> F_p = Do·E_p·Wst [128x2], qe_p = Do∘(E_p·bst) ----------------
// E0 = Wsk0 + Wsk1·G0 + Wsk2·C0 ; E1,E2 = Wsk1·G_p + Wsk2·C_p ; E3,E4 = Wsk2·C_p
__global__ __launch_bounds__(256) void k_prep3(const float* __restrict__ Gbuf,
        const float* __restrict__ Cbuf, const float* __restrict__ Wsk,
        const float* __restrict__ Wst, const float* __restrict__ bst,
        const float* __restrict__ og, const float* __restrict__ obt,
        const float* __restrict__ om, const float* __restrict__ ov,
        float* __restrict__ Fbuf, float* __restrict__ qbuf){
    __shared__ float E[128*128];                     // 64 KB
    int p = blockIdx.x, t = threadIdx.x;
    int o = t >> 1, c0 = (t & 1)*64;
    const float* W1 = Wsk + CD*CD;
    const float* W2 = Wsk + 2*CD*CD;
    const float* Gp = Gbuf + (size_t)p*16384;
    const float* Cp = Cbuf + (size_t)p*16384;
    float acc[64];
    #pragma unroll
    for (int cc=0; cc<64; cc++) acc[cc] = 0.f;
    if (p == 0){
        #pragma unroll
        for (int cc=0; cc<64; cc++) acc[cc] = Wsk[o*128 + c0 + cc];
    }
    for (int k = 0; k < 128; k++){
        float w2 = W2[o*128+k];
        const float* cr = Cp + k*128 + c0;
        if (p <= 2){
            float w1 = W1[o*128+k];
            const float* gr = Gp + k*128 + c0;
            #pragma unroll
            for (int cc=0; cc<64; cc++) acc[cc] += w1*gr[cc] + w2*cr[cc];
        } else {
            #pragma unroll
            for (int cc=0; cc<64; cc++) acc[cc] += w2*cr[cc];
        }
    }
    #pragma unroll
    for (int cc=0; cc<64; cc++) E[o*128 + c0 + cc] = acc[cc];
    __syncthreads();
    {   // F_p[o][cin], folded with output-BN scale Do
        int o2 = t >> 1, cin = t & 1;
        float Dov = og[o2]*rsqrtf(ov[o2]+1e-5f);
        float f = 0.f;
        for (int k = 0; k < 128; k++) f += E[o2*128+k]*Wst[k*2+cin];
        Fbuf[(p*2+cin)*CD + o2] = Dov*f;
    }
    if (t < 128){
        float Dov = og[t]*rsqrtf(ov[t]+1e-5f);
        float q = 0.f;
        for (int k = 0; k < 128; k++) q += E[t*128+k]*bst[k];
        q *= Dov;
        if (p == 0) q += obt[t] - om[t]*Dov;         // output-BN shift (r0 = 1)
        qbuf[p*CD + t] = q;
    }
}

// ---------------- prep4: bias-vector corrections into q0..q2 ----------------
__global__ __launch_bounds__(256) void k_prep4(const float* __restrict__ Gbuf,
        const float* __restrict__ Wsk, const float* __restrict__ bsk,
        const float* __restrict__ bgc,
        const float* __restrict__ gg, const float* __restrict__ gb,
        const float* __restrict__ gm, const float* __restrict__ gv,
        const float* __restrict__ bg, const float* __restrict__ bb,
        const float* __restrict__ bm, const float* __restrict__ bv,
        const float* __restrict__ og, const float* __restrict__ ov,
        float* __restrict__ qbuf){
    __shared__ float k1[128], k2[128], va[128], vb3[128], vc[128];
    int t = threadIdx.x;
    if (t < 128){
        #pragma unroll
        for (int i = 0; i < 2; i++){
            float Dg = gg[i*CD+t]*rsqrtf(gv[i*CD+t]+1e-5f);
            float Db = bg[i*CD+t]*rsqrtf(bv[i*CD+t]+1e-5f);
            float cg = gb[i*CD+t] - gm[i*CD+t]*Dg;
            float cb = bb[i*CD+t] - bm[i*CD+t]*Db;
            float kv = Db*(Dg*bgc[i*CD+t] + cg) + cb;
            if (i) k2[t] = kv; else k1[t] = kv;
        }
    }
    __syncthreads();
    if (t < 128){
        const float* H0 = Gbuf + (size_t)3*16384;
        const float* H1 = Gbuf + (size_t)4*16384;
        const float* H2 = Gbuf + (size_t)5*16384;
        float a=0.f, b=0.f, c=0.f;
        for (int k=0;k<128;k++){
            float kk = k1[k];
            a += H0[t*128+k]*kk; b += H1[t*128+k]*kk; c += H2[t*128+k]*kk;
        }
        va[t] = a + k2[t]; vb3[t] = b; vc[t] = c;
    }
    __syncthreads();
    if (t < 128){
        const float* W1 = Wsk + CD*CD;
        const float* W2 = Wsk + 2*CD*CD;
        float s1=0.f, s2=0.f, s3=0.f, s4=0.f;
        for (int k=0;k<128;k++){
            s1 += W1[t*128+k]*k1[k];
            s2 += W2[t*128+k]*va[k];
            s3 += W2[t*128+k]*vb3[k];
            s4 += W2[t*128+k]*vc[k];
        }
        float Dov = og[t]*rsqrtf(ov[t]+1e-5f);
        qbuf[t]        += Dov*(bsk[t] + bsk[CD+t] + bsk[2*CD+t] + s1 + s2);
        qbuf[CD + t]   += Dov*s3;
        qbuf[2*CD + t] += Dov*s4;
    }
}

// ---------------- rchain: r_p = 1^T A^p, p=0..4 ----------------
__global__ __launch_bounds__(256) void k_rchain(const float* __restrict__ adj,
        float* __restrict__ rbuf){
    __shared__ float rl[512], rn[512];
    int t = threadIdx.x;
    rl[t] = 1.f; rl[t+256] = 1.f;
    rbuf[t] = 1.f; rbuf[t+256] = 1.f;
    __syncthreads();
    for (int p = 1; p <= 4; p++){
        #pragma unroll
        for (int h = 0; h < 2; h++){
            int w = t + h*256;
            float s = 0.f;
            for (int v = 0; v < 512; v++) s += rl[v]*adj[(size_t)v*512 + w];
            rn[w] = s;
            rbuf[p*512 + w] = s;
        }
        __syncthreads();
        rl[t] = rn[t]; rl[t+256] = rn[t+256];
        __syncthreads();
    }
}

// ---------------- gather: Y0[(s*2+c)][n] = x0[b][c][n][t], s = b*12+t ----------------
__global__ __launch_bounds__(256) void k_gather(const float* __restrict__ x0,
        float* __restrict__ Y0){
    __shared__ float ld[128*13];
    int b = blockIdx.x >> 3, c = (blockIdx.x >> 2) & 1, nq = blockIdx.x & 3;
    int n0 = nq*128, t = threadIdx.x;
    const float* src = x0 + ((size_t)(b*2 + c)*NN + n0)*TT;
    for (int e = t; e < 128*TT; e += 256){
        int n = e / TT, tt = e - n*TT;
        ld[n*13 + tt] = src[e];
    }
    __syncthreads();
    for (int e = t; e < 128*TT; e += 256){
        int tt = e >> 7, n = e & 127;
        Y0[((size_t)(b*TT + tt)*2 + c)*NN + n0 + n] = ld[n*13 + tt];
    }
}

// ---------------- hop GEMM (fp32): DST[m][w] = sum_v SRC[m][v]·adj[v][w], M=1536 ----------------
__global__ __launch_bounds__(256) void k_hopf(const float* __restrict__ SRC,
        const float* __restrict__ adj, float* __restrict__ DST){
    __shared__ float Lt[16*68];   // [k=v][m 64 (+4)]
    __shared__ float Rt[16*68];   // [k=v][w 64 (+4)]
    const int t  = threadIdx.x;
    const int mb = (blockIdx.x >> 3) * 64;
    const int wb = (blockIdx.x & 7) * 64;
    const int tx = t & 15, ty = t >> 4;
    float acc[4][4] = {};
    for (int vb = 0; vb < 512; vb += 16){
        {   int cc = t >> 2, kg = (t & 3)*4;
            float4 x4 = *(const float4*)(SRC + (size_t)(mb+cc)*512 + vb + kg);
            Lt[(kg+0)*68+cc] = x4.x; Lt[(kg+1)*68+cc] = x4.y;
            Lt[(kg+2)*68+cc] = x4.z; Lt[(kg+3)*68+cc] = x4.w; }
        {   int k = t >> 4, w4 = (t & 15)*4;
            *(float4*)(Rt + k*68 + w4) = *(const float4*)(adj + (size_t)(vb+k)*512 + wb + w4); }
        __syncthreads();
        #pragma unroll
        for (int k = 0; k < 16; k++){
            float4 a4 = *(const float4*)(Lt + k*68 + ty*4);
            float4 b4 = *(const float4*)(Rt + k*68 + tx*4);
            float av[4] = {a4.x,a4.y,a4.z,a4.w};
            float bv2[4] = {b4.x,b4.y,b4.z,b4.w};
            #pragma unroll
            for (int i=0;i<4;i++)
                #pragma unroll
                for (int j=0;j<4;j++) acc[i][j] += av[i]*bv2[j];
        }
        __syncthreads();
    }
    #pragma unroll
    for (int i=0;i<4;i++){
        float4 q; q.x=acc[i][0]; q.y=acc[i][1]; q.z=acc[i][2]; q.w=acc[i][3];
        *(float4*)(DST + (size_t)(mb+ty*4+i)*512 + wb + tx*4) = q;
    }
}

// ---------------- final: out[s][n][o] = sum_k F[k][o]·Y[k][s][n] + sum_p q_p[o]·r_p[n] ----------------
__global__ __launch_bounds__(256) void k_final(const float* __restrict__ Ybuf,
        const float* __restrict__ Fbuf, const float* __restrict__ qbuf,
        const float* __restrict__ rbuf, float* __restrict__ out){
    __shared__ float Ys[10*256];
    __shared__ float rs[5*256];
    const int t = threadIdx.x;
    const int s = blockIdx.x >> 1;
    const int nh = (blockIdx.x & 1) * 256;
    #pragma unroll
    for (int k = 0; k < 10; k++){
        int p = k >> 1, c = k & 1;
        Ys[k*256 + t] = Ybuf[(size_t)p*1536*512 + ((size_t)s*2 + c)*512 + nh + t];
    }
    #pragma unroll
    for (int p = 0; p < 5; p++) rs[p*256 + t] = rbuf[p*512 + nh + t];
    float Fr[10][4], qr[5][4];
    const int o0 = (t & 31)*4;
    #pragma unroll
    for (int k = 0; k < 10; k++)
        #pragma unroll
        for (int j = 0; j < 4; j++) Fr[k][j] = Fbuf[k*CD + o0 + j];
    #pragma unroll
    for (int p = 0; p < 5; p++)
        #pragma unroll
        for (int j = 0; j < 4; j++) qr[p][j] = qbuf[p*CD + o0 + j];
    __syncthreads();
    float* Op = out + (size_t)s*SLICE + (size_t)nh*CD;
    const int ng = (t >> 5) * 32;
    for (int ni = 0; ni < 32; ni++){
        int n = ng + ni;
        float v[4];
        #pragma unroll
        for (int j=0;j<4;j++) v[j] = 0.f;
        #pragma unroll
        for (int p = 0; p < 5; p++){
            float rv = rs[p*256 + n];
            #pragma unroll
            for (int j=0;j<4;j++) v[j] += qr[p][j]*rv;
        }
        #pragma unroll
        for (int k = 0; k < 10; k++){
            float yv = Ys[k*256 + n];
            #pragma unroll
            for (int j=0;j<4;j++) v[j] += Fr[k][j]*yv;
        }
        float4 q; q.x=v[0]; q.y=v[1]; q.z=v[2]; q.w=v[3];
        *(float4*)(Op + (size_t)n*CD + o0) = q;
    }
}

extern "C" void kernel_launch(void* const* d_in, const int* in_sizes, int n_in,
                              void* d_out, int out_size, void* d_ws, size_t ws_size,
                              hipStream_t stream) {
    const float* x0   = (const float*)d_in[0];
    const float* adj  = (const float*)d_in[1];
    const float* Wst  = (const float*)d_in[2];
    const float* bst  = (const float*)d_in[3];
    const float* Wsk  = (const float*)d_in[4];
    const float* bsk  = (const float*)d_in[5];
    const float* Wgc  = (const float*)d_in[6];
    const float* bgc  = (const float*)d_in[7];
    const float* gg   = (const float*)d_in[8];
    const float* gb   = (const float*)d_in[9];
    const float* gm   = (const float*)d_in[10];
    const float* gv   = (const float*)d_in[11];
    const float* bg   = (const float*)d_in[12];
    const float* bb   = (const float*)d_in[13];
    const float* bm   = (const float*)d_in[14];
    const float* bv   = (const float*)d_in[15];
    const float* og   = (const float*)d_in[16];
    const float* obt  = (const float*)d_in[17];
    const float* om   = (const float*)d_in[18];
    const float* ov   = (const float*)d_in[19];
    float* out = (float*)d_out;            // [s][n][o]

    // ---- workspace (all fp32, ~16.5 MB) ----
    float* Gbuf = (float*)d_ws;            // 6 * 128*128
    float* Cbuf = Gbuf + 6*16384;          // 5 * 128*128
    float* Fbuf = Cbuf + 5*16384;          // 10 * 128
    float* qbuf = Fbuf + 10*CD;            // 5 * 128
    float* rbuf = qbuf + 5*CD;             // 5 * 512
    float* Ybuf = rbuf + 5*512;            // 5 * 1536*512

    // one-time affine collapse (all tiny)
    k_prep1<<<384, 256, 0, stream>>>(Wgc, gg, gb, gm, gv, bg, bb, bm, bv, Gbuf);
    k_prep2<<<20,  256, 0, stream>>>(Gbuf, Cbuf);
    k_prep3<<<5,   256, 0, stream>>>(Gbuf, Cbuf, Wsk, Wst, bst, og, obt, om, ov,
                                     Fbuf, qbuf);
    k_prep4<<<1,   256, 0, stream>>>(Gbuf, Wsk, bsk, bgc, gg, gb, gm, gv,
                                     bg, bb, bm, bv, og, ov, qbuf);
    k_rchain<<<1,  256, 0, stream>>>(adj, rbuf);

    // data path
    k_gather<<<512, 256, 0, stream>>>(x0, Ybuf);
    for (int p = 1; p <= 4; p++)
        k_hopf<<<192, 256, 0, stream>>>(Ybuf + (size_t)(p-1)*1536*512, adj,
                                        Ybuf + (size_t)p*1536*512);
    k_final<<<1536, 256, 0, stream>>>(Ybuf, Fbuf, qbuf, rbuf, out);
}